// Round 9
// baseline (466.897 us; speedup 1.0000x reference)
//
#include <hip/hip_runtime.h>
#include <hip/hip_bf16.h>

#define EPS_LN 1e-5f
#define NB    256             // edge chunks for hist/scatter
#define SEGCAP 16384          // srcList segment capacity per bucket (64KB LDS)

typedef int ivec4 __attribute__((ext_vector_type(4)));

// ===========================================================================
// R29: layer-boundary fusion. R28 accounting: agg x3 = 166us but ~200us sat
// in standalone gemms + 25.6MB-write/25.6MB-read f32 materialization at every
// layer boundary. Fuse:
//   fused_agg_gemm (512t, 64 nodes/blk): phase A = gather+bias+relu+LN into
//     LDS Asf[128][68] f32 (transposed: gemm A-frag = aligned conflict-free
//     float2); phase B = 64x128 gemm from LDS -> bf16 hb only (12.8MB).
//   agg_head (128t): layer-3 agg + collapsed head -> out (600KB).
// Deletes 3 x (25.6 write + 25.6 read) MB, 13 -> 10 kernels, and mixes
// gather-latency waves with FMA waves on each CU.
// ===========================================================================

__global__ __launch_bounds__(256) void bucket_hist(const int* __restrict__ col,
                                                   int* __restrict__ chunkBH,
                                                   int E, int per, int nbuck) {
    __shared__ int hist[256];
    int t = threadIdx.x;
    hist[t] = 0;
    __syncthreads();
    int s0 = blockIdx.x * per;
    int s1 = s0 + per; if (s1 > E) s1 = E;
    if (s0 < s1) {
        int q0 = s0 >> 2, q1 = s1 >> 2;
        for (int i = q0 + t; i < q1; i += 256) {
            ivec4 c = __builtin_nontemporal_load((const ivec4*)col + i);
            atomicAdd(&hist[c.x >> 8], 1);
            atomicAdd(&hist[c.y >> 8], 1);
            atomicAdd(&hist[c.z >> 8], 1);
            atomicAdd(&hist[c.w >> 8], 1);
        }
        for (int i = (q1 << 2) + t; i < s1; i += 256)
            atomicAdd(&hist[col[i] >> 8], 1);
    }
    __syncthreads();
    if (t < nbuck) chunkBH[blockIdx.x * 256 + t] = hist[t];   // [k][b], coalesced
}

__global__ __launch_bounds__(256) void bucket_scan(int* __restrict__ chunkBH,
                                                   int* __restrict__ bucketStart,
                                                   int* __restrict__ rowPtr,
                                                   int E, int n, int nbuck, int nb) {
    __shared__ int tot[256];
    int t = threadIdx.x;
    int run = 0;
    if (t < nbuck) {
        for (int k0 = 0; k0 < nb; k0 += 16) {
            int v[16];
#pragma unroll
            for (int j = 0; j < 16; j++)
                v[j] = (k0 + j < nb) ? chunkBH[(k0 + j) * 256 + t] : 0;
#pragma unroll
            for (int j = 0; j < 16; j++) {
                int tv = v[j];
                if (k0 + j < nb) chunkBH[(k0 + j) * 256 + t] = run;
                run += tv;
            }
        }
    }
    tot[t] = run;
    __syncthreads();
    for (int d = 1; d < 256; d <<= 1) {
        int add = (t >= d) ? tot[t - d] : 0;
        __syncthreads();
        tot[t] += add;
        __syncthreads();
    }
    if (t < nbuck) bucketStart[t] = tot[t] - run;
    if (t == 0) { bucketStart[nbuck] = E; rowPtr[n] = E; }
}

__global__ __launch_bounds__(256) void scatter_pairs(const int* __restrict__ row,
                                                     const int* __restrict__ col,
                                                     const int* __restrict__ chunkBH,
                                                     const int* __restrict__ bucketStart,
                                                     unsigned long long* __restrict__ tmp,
                                                     int E, int per, int nbuck) {
    __shared__ int curs[256];
    int t = threadIdx.x;
    int k = blockIdx.x;
    curs[t] = (t < nbuck) ? (chunkBH[k * 256 + t] + bucketStart[t]) : 0;
    __syncthreads();
    int s0 = k * per;
    int s1 = s0 + per; if (s1 > E) s1 = E;
    if (s0 >= s1) return;
    int q0 = s0 >> 2, q1 = s1 >> 2;
    for (int i = q0 + t; i < q1; i += 256) {
        ivec4 c4 = __builtin_nontemporal_load((const ivec4*)col + i);
        ivec4 r4 = __builtin_nontemporal_load((const ivec4*)row + i);
        int p0 = atomicAdd(&curs[c4.x >> 8], 1);
        tmp[p0] = ((unsigned long long)(unsigned)c4.x << 32) | (unsigned)r4.x;
        int p1 = atomicAdd(&curs[c4.y >> 8], 1);
        tmp[p1] = ((unsigned long long)(unsigned)c4.y << 32) | (unsigned)r4.y;
        int p2 = atomicAdd(&curs[c4.z >> 8], 1);
        tmp[p2] = ((unsigned long long)(unsigned)c4.z << 32) | (unsigned)r4.z;
        int p3 = atomicAdd(&curs[c4.w >> 8], 1);
        tmp[p3] = ((unsigned long long)(unsigned)c4.w << 32) | (unsigned)r4.w;
    }
    for (int i = (q1 << 2) + t; i < s1; i += 256) {
        int c = col[i], r = row[i];
        int p = atomicAdd(&curs[c >> 8], 1);
        tmp[p] = ((unsigned long long)(unsigned)c << 32) | (unsigned)r;
    }
}

__global__ __launch_bounds__(256) void bucket_fill(const unsigned long long* __restrict__ tmp,
                                                   const int* __restrict__ bucketStart,
                                                   int* __restrict__ rowPtr,
                                                   float* __restrict__ dinv,
                                                   int* __restrict__ srcList,
                                                   int n) {
    __shared__ int cnt[256];
    __shared__ int cur[256];
    __shared__ int seg[SEGCAP];
    int b = blockIdx.x, t = threadIdx.x;
    int node0 = b << 8;
    int s0 = bucketStart[b], s1 = bucketStart[b + 1];
    int len = s1 - s0;
    cnt[t] = 0;
    __syncthreads();
    for (int i = s0 + t; i < s1; i += 256) {
        int c = (int)(tmp[i] >> 32);
        atomicAdd(&cnt[c - node0], 1);
    }
    __syncthreads();
    int v = cnt[t];
    cur[t] = v;
    __syncthreads();
    for (int d = 1; d < 256; d <<= 1) {
        int add = (t >= d) ? cur[t - d] : 0;
        __syncthreads();
        cur[t] += add;
        __syncthreads();
    }
    int excl = cur[t] - v;
    int node = node0 + t;
    if (node < n) {
        rowPtr[node] = s0 + excl;
        dinv[node] = rsqrtf((float)v + 1.0f);   // +1 self-loop
    }
    cur[t] = excl;
    __syncthreads();
    if (len <= SEGCAP) {
        for (int i = s0 + t; i < s1; i += 256) {
            unsigned long long p = tmp[i];
            int c = (int)(p >> 32);
            int r = (int)(p & 0xffffffffu);
            int pos = atomicAdd(&cur[c - node0], 1);
            seg[pos] = r;
        }
        __syncthreads();
        for (int i = t; i < len; i += 256)
            srcList[s0 + i] = seg[i];
    } else {                                    // overflow fallback (never for this graph)
        for (int i = s0 + t; i < s1; i += 256) {
            unsigned long long p = tmp[i];
            int c = (int)(p >> 32);
            int r = (int)(p & 0xffffffffu);
            int pos = atomicAdd(&cur[c - node0], 1);
            srcList[s0 + pos] = r;
        }
    }
}

// ---------------------------------------------------------------------------
// GEMM (layer 1 only): 64x128 tile, 256 threads, emits bf16 hb = (A@W)*dinv.
// ---------------------------------------------------------------------------
__global__ __launch_bounds__(256) void gemm_hb(const float* __restrict__ A,
                                               const float* __restrict__ W,
                                               const float* __restrict__ dinv,
                                               unsigned short* __restrict__ Cb,
                                               int n) {
    __shared__ float As[16][68];
    __shared__ float Ws[16][144];

    const int tx = threadIdx.x;
    const int row0 = blockIdx.x * 64;
    const int jg = (tx & 15) * 8;
    const int ig = (tx >> 4) * 4;
    const int js = jg + ((jg >> 5) << 2);

    const int ar  = tx >> 2;
    const int ac4 = (tx & 3) * 4;
    const int growA = row0 + ar;
    const float* Ap = A + (size_t)growA * 128 + ac4;

    float acc[4][8];
#pragma unroll
    for (int r = 0; r < 4; r++)
#pragma unroll
        for (int c = 0; c < 8; c++) acc[r][c] = 0.f;

    for (int k0 = 0; k0 < 128; k0 += 16) {
        float4 va = make_float4(0.f, 0.f, 0.f, 0.f);
        if (growA < n) va = *(const float4*)(Ap + k0);
        As[ac4 + 0][ar] = va.x;
        As[ac4 + 1][ar] = va.y;
        As[ac4 + 2][ar] = va.z;
        As[ac4 + 3][ar] = va.w;
#pragma unroll
        for (int q = 0; q < 2; q++) {
            int f = tx * 2 + q;
            int kr = f >> 5;
            int c4 = (f & 31) * 4;
            int cs = c4 + ((c4 >> 5) << 2);
            *(float4*)&Ws[kr][cs] = *(const float4*)(W + (size_t)(k0 + kr) * 128 + c4);
        }
        __syncthreads();
#pragma unroll
        for (int kk = 0; kk < 16; kk++) {
            float4 a4 = *(const float4*)&As[kk][ig];
            float4 w0 = *(const float4*)&Ws[kk][js];
            float4 w1 = *(const float4*)&Ws[kk][js + 4];
            float av[4] = {a4.x, a4.y, a4.z, a4.w};
            float wv[8] = {w0.x, w0.y, w0.z, w0.w, w1.x, w1.y, w1.z, w1.w};
#pragma unroll
            for (int r = 0; r < 4; r++)
#pragma unroll
                for (int c = 0; c < 8; c++) acc[r][c] += av[r] * wv[c];
        }
        __syncthreads();
    }

#pragma unroll
    for (int r = 0; r < 4; r++) {
        int grow = row0 + ig + r;
        if (grow < n) {
            float dr = dinv[grow];
            ushort4 u0, u1;
            __hip_bfloat16 t;
            t = __float2bfloat16(acc[r][0] * dr); u0.x = *(unsigned short*)&t;
            t = __float2bfloat16(acc[r][1] * dr); u0.y = *(unsigned short*)&t;
            t = __float2bfloat16(acc[r][2] * dr); u0.z = *(unsigned short*)&t;
            t = __float2bfloat16(acc[r][3] * dr); u0.w = *(unsigned short*)&t;
            t = __float2bfloat16(acc[r][4] * dr); u1.x = *(unsigned short*)&t;
            t = __float2bfloat16(acc[r][5] * dr); u1.y = *(unsigned short*)&t;
            t = __float2bfloat16(acc[r][6] * dr); u1.z = *(unsigned short*)&t;
            t = __float2bfloat16(acc[r][7] * dr); u1.w = *(unsigned short*)&t;
            *(ushort4*)(Cb + (size_t)grow * 128 + jg)     = u0;
            *(ushort4*)(Cb + (size_t)grow * 128 + jg + 4) = u1;
        }
    }
}

#define BF_LO(u) __uint_as_float((u) << 16)
#define BF_HI(u) __uint_as_float((u) & 0xffff0000u)

// ---------------------------------------------------------------------------
// Fused agg(LN) + gemm: 512 threads, 64 nodes/block.
// Phase A: wave wv aggregates nodes base+wv*8 .. +7 (R28 gather structure),
// result (post bias+relu+LN) -> Asf[feat][node] in LDS (f32).
// Phase B: 64x128 gemm from Asf -> bf16 hbOut = (h@W)*dinv.
// ---------------------------------------------------------------------------
__global__ __launch_bounds__(512) void fused_agg_gemm(
        const unsigned int* __restrict__ hb,
        const int* __restrict__ rowPtr,
        const int* __restrict__ srcList,
        const float* __restrict__ dinv,
        const float* __restrict__ b,
        const float* __restrict__ g,
        const float* __restrict__ beta,
        const float* __restrict__ W,
        unsigned short* __restrict__ hbOut,
        int n) {
    __shared__ float Asf[128][68];
    __shared__ float Ws[16][144];

    const int tx = threadIdx.x;
    const int base = blockIdx.x * 64;
    const int wv = tx >> 6;           // wave 0..7
    const int lane = tx & 63;
    const int h = lane & 15;          // feature octet
    const int gg = lane >> 4;         // edge group
    const uint4* hb4 = (const uint4*)hb;

    // ---- Phase A: aggregate 8 nodes per wave ----
    for (int it = 0; it < 8; ++it) {
        int wid = base + wv * 8 + it;
        if (wid >= n) break;
        int e0 = rowPtr[wid], e1 = rowPtr[wid + 1];
        float dc = dinv[wid];
        uint4 us = hb4[(size_t)wid * 16 + h];

        float a[8];
#pragma unroll
        for (int j = 0; j < 8; j++) a[j] = 0.f;

        int idx0 = (e0 + gg < e1) ? srcList[e0 + gg] : -1;
        int idx1 = (e0 + 4 + gg < e1) ? srcList[e0 + 4 + gg] : -1;
        int e = e0;
        for (; e + 8 <= e1; e += 8) {
            int ni0 = (e + 8 + gg < e1) ? srcList[e + 8 + gg] : -1;
            int ni1 = (e + 12 + gg < e1) ? srcList[e + 12 + gg] : -1;
            uint4 u0 = hb4[(size_t)idx0 * 16 + h];
            uint4 u1 = hb4[(size_t)idx1 * 16 + h];
            a[0] += BF_LO(u0.x); a[1] += BF_HI(u0.x);
            a[2] += BF_LO(u0.y); a[3] += BF_HI(u0.y);
            a[4] += BF_LO(u0.z); a[5] += BF_HI(u0.z);
            a[6] += BF_LO(u0.w); a[7] += BF_HI(u0.w);
            a[0] += BF_LO(u1.x); a[1] += BF_HI(u1.x);
            a[2] += BF_LO(u1.y); a[3] += BF_HI(u1.y);
            a[4] += BF_LO(u1.z); a[5] += BF_HI(u1.z);
            a[6] += BF_LO(u1.w); a[7] += BF_HI(u1.w);
            idx0 = ni0; idx1 = ni1;
        }
        if (idx0 >= 0) {
            uint4 u = hb4[(size_t)idx0 * 16 + h];
            a[0] += BF_LO(u.x); a[1] += BF_HI(u.x);
            a[2] += BF_LO(u.y); a[3] += BF_HI(u.y);
            a[4] += BF_LO(u.z); a[5] += BF_HI(u.z);
            a[6] += BF_LO(u.w); a[7] += BF_HI(u.w);
        }
        if (idx1 >= 0) {
            uint4 u = hb4[(size_t)idx1 * 16 + h];
            a[0] += BF_LO(u.x); a[1] += BF_HI(u.x);
            a[2] += BF_LO(u.y); a[3] += BF_HI(u.y);
            a[4] += BF_LO(u.z); a[5] += BF_HI(u.z);
            a[6] += BF_LO(u.w); a[7] += BF_HI(u.w);
        }
#pragma unroll
        for (int j = 0; j < 8; j++) {
            a[j] += __shfl_xor(a[j], 16, 64);
            a[j] += __shfl_xor(a[j], 32, 64);
        }
        a[0] += BF_LO(us.x); a[1] += BF_HI(us.x);
        a[2] += BF_LO(us.y); a[3] += BF_HI(us.y);
        a[4] += BF_LO(us.z); a[5] += BF_HI(us.z);
        a[6] += BF_LO(us.w); a[7] += BF_HI(us.w);

        float4 bv0 = *(const float4*)(b + h * 8);
        float4 bv1 = *(const float4*)(b + h * 8 + 4);
        a[0] = fmaxf(a[0] * dc + bv0.x, 0.f);
        a[1] = fmaxf(a[1] * dc + bv0.y, 0.f);
        a[2] = fmaxf(a[2] * dc + bv0.z, 0.f);
        a[3] = fmaxf(a[3] * dc + bv0.w, 0.f);
        a[4] = fmaxf(a[4] * dc + bv1.x, 0.f);
        a[5] = fmaxf(a[5] * dc + bv1.y, 0.f);
        a[6] = fmaxf(a[6] * dc + bv1.z, 0.f);
        a[7] = fmaxf(a[7] * dc + bv1.w, 0.f);

        // LayerNorm (wave-internal)
        float s = ((a[0] + a[1]) + (a[2] + a[3])) + ((a[4] + a[5]) + (a[6] + a[7]));
#pragma unroll
        for (int m = 8; m >= 1; m >>= 1) s += __shfl_xor(s, m, 64);
        float mu = s * (1.f / 128.f);
        float sq = 0.f;
        float d[8];
#pragma unroll
        for (int j = 0; j < 8; j++) { d[j] = a[j] - mu; sq += d[j] * d[j]; }
#pragma unroll
        for (int m = 8; m >= 1; m >>= 1) sq += __shfl_xor(sq, m, 64);
        float rs = rsqrtf(sq * (1.f / 128.f) + EPS_LN);
        float4 gv0 = *(const float4*)(g + h * 8);
        float4 gv1 = *(const float4*)(g + h * 8 + 4);
        float4 bt0 = *(const float4*)(beta + h * 8);
        float4 bt1 = *(const float4*)(beta + h * 8 + 4);
        a[0] = d[0] * rs * gv0.x + bt0.x;
        a[1] = d[1] * rs * gv0.y + bt0.y;
        a[2] = d[2] * rs * gv0.z + bt0.z;
        a[3] = d[3] * rs * gv0.w + bt0.w;
        a[4] = d[4] * rs * gv1.x + bt1.x;
        a[5] = d[5] * rs * gv1.y + bt1.y;
        a[6] = d[6] * rs * gv1.z + bt1.z;
        a[7] = d[7] * rs * gv1.w + bt1.w;

        // stage into LDS (transposed): lane (h,gg) writes feats 8h+2gg,+1
        int c = wv * 8 + it;
        int f0 = 8 * h + 2 * gg;
        Asf[f0][c]     = a[2 * gg];
        Asf[f0 + 1][c] = a[2 * gg + 1];
    }
    __syncthreads();

    // ---- Phase B: 64x128 gemm from Asf ----
    const int jg = (tx & 15) * 8;
    const int ig = (tx >> 4) * 2;         // 0..62
    const int js = jg + ((jg >> 5) << 2);
    float acc[2][8];
#pragma unroll
    for (int r = 0; r < 2; r++)
#pragma unroll
        for (int cc = 0; cc < 8; cc++) acc[r][cc] = 0.f;

    for (int k0 = 0; k0 < 128; k0 += 16) {
        {
            int kr = tx >> 5;              // 0..15
            int c4 = (tx & 31) * 4;
            int cs = c4 + ((c4 >> 5) << 2);
            *(float4*)&Ws[kr][cs] = *(const float4*)(W + (size_t)(k0 + kr) * 128 + c4);
        }
        __syncthreads();
#pragma unroll
        for (int kk = 0; kk < 16; kk++) {
            float2 a2 = *(const float2*)&Asf[k0 + kk][ig];
            float4 w0 = *(const float4*)&Ws[kk][js];
            float4 w1 = *(const float4*)&Ws[kk][js + 4];
            float wvv[8] = {w0.x, w0.y, w0.z, w0.w, w1.x, w1.y, w1.z, w1.w};
#pragma unroll
            for (int cc = 0; cc < 8; cc++) {
                acc[0][cc] += a2.x * wvv[cc];
                acc[1][cc] += a2.y * wvv[cc];
            }
        }
        __syncthreads();
    }

#pragma unroll
    for (int r = 0; r < 2; r++) {
        int grow = base + ig + r;
        if (grow < n) {
            float dr = dinv[grow];
            ushort4 u0, u1;
            __hip_bfloat16 t;
            t = __float2bfloat16(acc[r][0] * dr); u0.x = *(unsigned short*)&t;
            t = __float2bfloat16(acc[r][1] * dr); u0.y = *(unsigned short*)&t;
            t = __float2bfloat16(acc[r][2] * dr); u0.z = *(unsigned short*)&t;
            t = __float2bfloat16(acc[r][3] * dr); u0.w = *(unsigned short*)&t;
            t = __float2bfloat16(acc[r][4] * dr); u1.x = *(unsigned short*)&t;
            t = __float2bfloat16(acc[r][5] * dr); u1.y = *(unsigned short*)&t;
            t = __float2bfloat16(acc[r][6] * dr); u1.z = *(unsigned short*)&t;
            t = __float2bfloat16(acc[r][7] * dr); u1.w = *(unsigned short*)&t;
            *(ushort4*)(hbOut + (size_t)grow * 128 + jg)     = u0;
            *(ushort4*)(hbOut + (size_t)grow * 128 + jg + 4) = u1;
        }
    }
}

// ---------------------------------------------------------------------------
// Fused layer-3 agg (relu, no LN) + collapsed head: out = h @ Weff + beff.
// ---------------------------------------------------------------------------
__global__ __launch_bounds__(128) void agg_head(
        const unsigned int* __restrict__ hb,
        const int* __restrict__ rowPtr,
        const int* __restrict__ srcList,
        const float* __restrict__ dinv,
        const float* __restrict__ b,
        const float* __restrict__ Weff,
        const float* __restrict__ beff,
        float* __restrict__ out, int n) {
    __shared__ float Wl[384];
    int tt = threadIdx.x;
    Wl[tt] = Weff[tt]; Wl[tt + 128] = Weff[tt + 128]; Wl[tt + 256] = Weff[tt + 256];
    __syncthreads();

    int wid = (blockIdx.x * 128 + tt) >> 6;
    int lane = tt & 63;
    if (wid >= n) return;
    int h = lane & 15;
    int gg = lane >> 4;
    int e0 = rowPtr[wid], e1 = rowPtr[wid + 1];
    float dc = dinv[wid];
    const uint4* hb4 = (const uint4*)hb;
    uint4 us = hb4[(size_t)wid * 16 + h];

    float a[8];
#pragma unroll
    for (int j = 0; j < 8; j++) a[j] = 0.f;

    int idx0 = (e0 + gg < e1) ? srcList[e0 + gg] : -1;
    int idx1 = (e0 + 4 + gg < e1) ? srcList[e0 + 4 + gg] : -1;
    int e = e0;
    for (; e + 8 <= e1; e += 8) {
        int ni0 = (e + 8 + gg < e1) ? srcList[e + 8 + gg] : -1;
        int ni1 = (e + 12 + gg < e1) ? srcList[e + 12 + gg] : -1;
        uint4 u0 = hb4[(size_t)idx0 * 16 + h];
        uint4 u1 = hb4[(size_t)idx1 * 16 + h];
        a[0] += BF_LO(u0.x); a[1] += BF_HI(u0.x);
        a[2] += BF_LO(u0.y); a[3] += BF_HI(u0.y);
        a[4] += BF_LO(u0.z); a[5] += BF_HI(u0.z);
        a[6] += BF_LO(u0.w); a[7] += BF_HI(u0.w);
        a[0] += BF_LO(u1.x); a[1] += BF_HI(u1.x);
        a[2] += BF_LO(u1.y); a[3] += BF_HI(u1.y);
        a[4] += BF_LO(u1.z); a[5] += BF_HI(u1.z);
        a[6] += BF_LO(u1.w); a[7] += BF_HI(u1.w);
        idx0 = ni0; idx1 = ni1;
    }
    if (idx0 >= 0) {
        uint4 u = hb4[(size_t)idx0 * 16 + h];
        a[0] += BF_LO(u.x); a[1] += BF_HI(u.x);
        a[2] += BF_LO(u.y); a[3] += BF_HI(u.y);
        a[4] += BF_LO(u.z); a[5] += BF_HI(u.z);
        a[6] += BF_LO(u.w); a[7] += BF_HI(u.w);
    }
    if (idx1 >= 0) {
        uint4 u = hb4[(size_t)idx1 * 16 + h];
        a[0] += BF_LO(u.x); a[1] += BF_HI(u.x);
        a[2] += BF_LO(u.y); a[3] += BF_HI(u.y);
        a[4] += BF_LO(u.z); a[5] += BF_HI(u.z);
        a[6] += BF_LO(u.w); a[7] += BF_HI(u.w);
    }
#pragma unroll
    for (int j = 0; j < 8; j++) {
        a[j] += __shfl_xor(a[j], 16, 64);
        a[j] += __shfl_xor(a[j], 32, 64);
    }
    a[0] += BF_LO(us.x); a[1] += BF_HI(us.x);
    a[2] += BF_LO(us.y); a[3] += BF_HI(us.y);
    a[4] += BF_LO(us.z); a[5] += BF_HI(us.z);
    a[6] += BF_LO(us.w); a[7] += BF_HI(us.w);

    float4 bv0 = *(const float4*)(b + h * 8);
    float4 bv1 = *(const float4*)(b + h * 8 + 4);
    a[0] = fmaxf(a[0] * dc + bv0.x, 0.f);
    a[1] = fmaxf(a[1] * dc + bv0.y, 0.f);
    a[2] = fmaxf(a[2] * dc + bv0.z, 0.f);
    a[3] = fmaxf(a[3] * dc + bv0.w, 0.f);
    a[4] = fmaxf(a[4] * dc + bv1.x, 0.f);
    a[5] = fmaxf(a[5] * dc + bv1.y, 0.f);
    a[6] = fmaxf(a[6] * dc + bv1.z, 0.f);
    a[7] = fmaxf(a[7] * dc + bv1.w, 0.f);

    // head: p_j = sum over this lane's 8 feats, then reduce over h (lanes 0-15)
    float p0 = 0.f, p1 = 0.f, p2 = 0.f;
#pragma unroll
    for (int j = 0; j < 8; j++) {
        const float* w = &Wl[(8 * h + j) * 3];
        p0 += a[j] * w[0];
        p1 += a[j] * w[1];
        p2 += a[j] * w[2];
    }
#pragma unroll
    for (int m = 8; m >= 1; m >>= 1) {
        p0 += __shfl_xor(p0, m, 64);
        p1 += __shfl_xor(p1, m, 64);
        p2 += __shfl_xor(p2, m, 64);
    }
    if (lane == 0) {
        out[(size_t)wid * 3 + 0] = p0 + beff[0];
        out[(size_t)wid * 3 + 1] = p1 + beff[1];
        out[(size_t)wid * 3 + 2] = p2 + beff[2];
    }
}

// ---------------------------------------------------------------------------
// Head collapse: Weff = Wp1 @ Wp2 (128x3), beff = bp1 @ Wp2 + bp2.
// ---------------------------------------------------------------------------
__global__ __launch_bounds__(128) void head_collapse(const float* __restrict__ Wp1,
                                                     const float* __restrict__ bp1,
                                                     const float* __restrict__ Wp2,
                                                     const float* __restrict__ bp2,
                                                     float* __restrict__ Weff,
                                                     float* __restrict__ beff) {
    __shared__ float w2[384];
    int t = threadIdx.x;
    w2[t] = Wp2[t]; w2[t + 128] = Wp2[t + 128]; w2[t + 256] = Wp2[t + 256];
    __syncthreads();
    float p0 = 0.f, p1 = 0.f, p2 = 0.f;
    const float* wr = Wp1 + (size_t)t * 128;
    for (int k = 0; k < 128; k++) {
        float v = wr[k];
        p0 += v * w2[k * 3 + 0];
        p1 += v * w2[k * 3 + 1];
        p2 += v * w2[k * 3 + 2];
    }
    Weff[t * 3 + 0] = p0; Weff[t * 3 + 1] = p1; Weff[t * 3 + 2] = p2;
    if (t == 0) {
        float q0 = bp2[0], q1 = bp2[1], q2 = bp2[2];
        for (int k = 0; k < 128; k++) {
            float v = bp1[k];
            q0 += v * w2[k * 3 + 0];
            q1 += v * w2[k * 3 + 1];
            q2 += v * w2[k * 3 + 2];
        }
        beff[0] = q0; beff[1] = q1; beff[2] = q2;
    }
}

// ---------------------------------------------------------------------------
extern "C" void kernel_launch(void* const* d_in, const int* in_sizes, int n_in,
                              void* d_out, int out_size, void* d_ws, size_t ws_size,
                              hipStream_t stream) {
    const float* x   = (const float*)d_in[0];
    const int* ei    = (const int*)d_in[1];
    const float* W1  = (const float*)d_in[2];
    const float* b1  = (const float*)d_in[3];
    const float* W2  = (const float*)d_in[4];
    const float* b2  = (const float*)d_in[5];
    const float* W3  = (const float*)d_in[6];
    const float* b3  = (const float*)d_in[7];
    const float* g1  = (const float*)d_in[8];
    const float* be1 = (const float*)d_in[9];
    const float* g2  = (const float*)d_in[10];
    const float* be2 = (const float*)d_in[11];
    const float* Wp1 = (const float*)d_in[12];
    const float* bp1 = (const float*)d_in[13];
    const float* Wp2 = (const float*)d_in[14];
    const float* bp2 = (const float*)d_in[15];
    float* out = (float*)d_out;

    const int n = in_sizes[0] / 128;   // 50000
    const int E = in_sizes[1] / 2;     // 1600000
    const int* row = ei;
    const int* col = ei + E;

    char* ws = (char*)d_ws;
    size_t nA  = ((size_t)n * 4 + 255) & ~(size_t)255;
    size_t nA1 = ((size_t)(n + 1) * 4 + 255) & ~(size_t)255;
    size_t eA  = ((size_t)E * 4 + 255) & ~(size_t)255;
    size_t hbA_sz = ((size_t)n * 128 * 2 + 255) & ~(size_t)255;
    int*   rowPtr  = (int*)ws;
    float* dinvp   = (float*)(ws + nA1);
    int*   srcList = (int*)(ws + nA1 + nA);
    unsigned short* hbA = (unsigned short*)(ws + nA1 + nA + eA);
    float* bufA    = (float*)(ws + nA1 + nA + eA + hbA_sz);
    float* bufB    = bufA + (size_t)n * 128;
    unsigned short* hbB = (unsigned short*)bufA;   // 12.8MB, after CSR scratch dies
    float* Weff    = bufB;                         // 384 floats
    float* beff    = bufB + 384;                   // 3 floats
    // CSR scratch aliases bufA (consumed by bucket_fill before any hbB write):
    unsigned long long* tmp = (unsigned long long*)bufA;
    int* chunkBH    = (int*)((char*)bufA + 2 * eA);
    int* bucketStart = (int*)((char*)bufA + 2 * eA + (size_t)NB * 256 * 4);

    const int nbuck = (n + 255) >> 8;                 // 196
    const int per   = (((E + NB - 1) / NB) + 15) & ~15;
    const int tileBlocks = (n + 63) / 64;             // 782
    const int nodeWaveBlocks = (n + 1) / 2;           // 25000

    // CSR build (bucketed counting sort, zero global atomics)
    bucket_hist<<<NB, 256, 0, stream>>>(col, chunkBH, E, per, nbuck);
    bucket_scan<<<1, 256, 0, stream>>>(chunkBH, bucketStart, rowPtr, E, n, nbuck, NB);
    scatter_pairs<<<NB, 256, 0, stream>>>(row, col, chunkBH, bucketStart, tmp, E, per, nbuck);
    bucket_fill<<<nbuck, 256, 0, stream>>>(tmp, bucketStart, rowPtr, dinvp, srcList, n);
    head_collapse<<<1, 128, 0, stream>>>(Wp1, bp1, Wp2, bp2, Weff, beff);

    // layer 1 gemm: x @ W1 -> hbA (bias b1 folded into agg phase of K2)
    gemm_hb<<<tileBlocks, 256, 0, stream>>>(x, W1, dinvp, hbA, n);
    // K2: agg(LN1) + gemm W2 -> hbB
    fused_agg_gemm<<<tileBlocks, 512, 0, stream>>>((const unsigned int*)hbA,
                                                   rowPtr, srcList, dinvp,
                                                   b1, g1, be1, W2, hbB, n);
    // K3: agg(LN2) + gemm W3 -> hbA
    fused_agg_gemm<<<tileBlocks, 512, 0, stream>>>((const unsigned int*)hbB,
                                                   rowPtr, srcList, dinvp,
                                                   b2, g2, be2, W3, hbA, n);
    // K4: agg(relu) + collapsed head -> out
    agg_head<<<nodeWaveBlocks, 128, 0, stream>>>((const unsigned int*)hbA,
                                                 rowPtr, srcList, dinvp,
                                                 b3, Weff, beff, out, n);
}

// Round 10
// 414.295 us; speedup vs baseline: 1.1270x; 1.1270x over previous
//
#include <hip/hip_runtime.h>
#include <hip/hip_bf16.h>

#define EPS_LN 1e-5f
#define NB    256             // edge chunks for hist/scatter
#define SEGCAP 16384          // srcList segment capacity per bucket (64KB LDS)

typedef int ivec4 __attribute__((ext_vector_type(4)));
typedef short bf16x8v __attribute__((ext_vector_type(8)));
typedef float f32x4v __attribute__((ext_vector_type(4)));

// ===========================================================================
// R30: revert R29 fusion (regression: 32% occupancy + 9.4M LDS conflicts +
// phase serialization). Back to R28 structure, replacing the f32 VALU gemm
// (~50-65us each, 5x floor, MfmaUtil=0) with an MFMA gemm:
//   - operands split f32 -> hi+lo bf16 (rel err ~2^-17): 3 MFMA/tile
//     (ah*bh + ah*bl + al*bh) gives ~f32 accuracy at negligible MFMA cost.
//   - pack_w: one-time pack of W into B-fragment order (hi/lo planes).
//   - cast_hilo: one-time x -> bf16 hi/lo planes.
//   - agg_post writes hi/lo bf16 planes (same bytes as old f32 write).
//   - agg_head (R29's, correct) fuses layer-3 agg + collapsed head.
// MFMA 16x16x32_bf16 layouts: A row=lane&15, k=8*(lane>>4)+i;
// C/D col=lane&15, row=(lane>>4)*4+reg (guide m89-verified).
// ===========================================================================

__global__ __launch_bounds__(256) void bucket_hist(const int* __restrict__ col,
                                                   int* __restrict__ chunkBH,
                                                   int E, int per, int nbuck) {
    __shared__ int hist[256];
    int t = threadIdx.x;
    hist[t] = 0;
    __syncthreads();
    int s0 = blockIdx.x * per;
    int s1 = s0 + per; if (s1 > E) s1 = E;
    if (s0 < s1) {
        int q0 = s0 >> 2, q1 = s1 >> 2;
        for (int i = q0 + t; i < q1; i += 256) {
            ivec4 c = __builtin_nontemporal_load((const ivec4*)col + i);
            atomicAdd(&hist[c.x >> 8], 1);
            atomicAdd(&hist[c.y >> 8], 1);
            atomicAdd(&hist[c.z >> 8], 1);
            atomicAdd(&hist[c.w >> 8], 1);
        }
        for (int i = (q1 << 2) + t; i < s1; i += 256)
            atomicAdd(&hist[col[i] >> 8], 1);
    }
    __syncthreads();
    if (t < nbuck) chunkBH[blockIdx.x * 256 + t] = hist[t];   // [k][b], coalesced
}

__global__ __launch_bounds__(256) void bucket_scan(int* __restrict__ chunkBH,
                                                   int* __restrict__ bucketStart,
                                                   int* __restrict__ rowPtr,
                                                   int E, int n, int nbuck, int nb) {
    __shared__ int tot[256];
    int t = threadIdx.x;
    int run = 0;
    if (t < nbuck) {
        for (int k0 = 0; k0 < nb; k0 += 16) {
            int v[16];
#pragma unroll
            for (int j = 0; j < 16; j++)
                v[j] = (k0 + j < nb) ? chunkBH[(k0 + j) * 256 + t] : 0;
#pragma unroll
            for (int j = 0; j < 16; j++) {
                int tv = v[j];
                if (k0 + j < nb) chunkBH[(k0 + j) * 256 + t] = run;
                run += tv;
            }
        }
    }
    tot[t] = run;
    __syncthreads();
    for (int d = 1; d < 256; d <<= 1) {
        int add = (t >= d) ? tot[t - d] : 0;
        __syncthreads();
        tot[t] += add;
        __syncthreads();
    }
    if (t < nbuck) bucketStart[t] = tot[t] - run;
    if (t == 0) { bucketStart[nbuck] = E; rowPtr[n] = E; }
}

__global__ __launch_bounds__(256) void scatter_pairs(const int* __restrict__ row,
                                                     const int* __restrict__ col,
                                                     const int* __restrict__ chunkBH,
                                                     const int* __restrict__ bucketStart,
                                                     unsigned long long* __restrict__ tmp,
                                                     int E, int per, int nbuck) {
    __shared__ int curs[256];
    int t = threadIdx.x;
    int k = blockIdx.x;
    curs[t] = (t < nbuck) ? (chunkBH[k * 256 + t] + bucketStart[t]) : 0;
    __syncthreads();
    int s0 = k * per;
    int s1 = s0 + per; if (s1 > E) s1 = E;
    if (s0 >= s1) return;
    int q0 = s0 >> 2, q1 = s1 >> 2;
    for (int i = q0 + t; i < q1; i += 256) {
        ivec4 c4 = __builtin_nontemporal_load((const ivec4*)col + i);
        ivec4 r4 = __builtin_nontemporal_load((const ivec4*)row + i);
        int p0 = atomicAdd(&curs[c4.x >> 8], 1);
        tmp[p0] = ((unsigned long long)(unsigned)c4.x << 32) | (unsigned)r4.x;
        int p1 = atomicAdd(&curs[c4.y >> 8], 1);
        tmp[p1] = ((unsigned long long)(unsigned)c4.y << 32) | (unsigned)r4.y;
        int p2 = atomicAdd(&curs[c4.z >> 8], 1);
        tmp[p2] = ((unsigned long long)(unsigned)c4.z << 32) | (unsigned)r4.z;
        int p3 = atomicAdd(&curs[c4.w >> 8], 1);
        tmp[p3] = ((unsigned long long)(unsigned)c4.w << 32) | (unsigned)r4.w;
    }
    for (int i = (q1 << 2) + t; i < s1; i += 256) {
        int c = col[i], r = row[i];
        int p = atomicAdd(&curs[c >> 8], 1);
        tmp[p] = ((unsigned long long)(unsigned)c << 32) | (unsigned)r;
    }
}

__global__ __launch_bounds__(256) void bucket_fill(const unsigned long long* __restrict__ tmp,
                                                   const int* __restrict__ bucketStart,
                                                   int* __restrict__ rowPtr,
                                                   float* __restrict__ dinv,
                                                   int* __restrict__ srcList,
                                                   int n) {
    __shared__ int cnt[256];
    __shared__ int cur[256];
    __shared__ int seg[SEGCAP];
    int b = blockIdx.x, t = threadIdx.x;
    int node0 = b << 8;
    int s0 = bucketStart[b], s1 = bucketStart[b + 1];
    int len = s1 - s0;
    cnt[t] = 0;
    __syncthreads();
    for (int i = s0 + t; i < s1; i += 256) {
        int c = (int)(tmp[i] >> 32);
        atomicAdd(&cnt[c - node0], 1);
    }
    __syncthreads();
    int v = cnt[t];
    cur[t] = v;
    __syncthreads();
    for (int d = 1; d < 256; d <<= 1) {
        int add = (t >= d) ? cur[t - d] : 0;
        __syncthreads();
        cur[t] += add;
        __syncthreads();
    }
    int excl = cur[t] - v;
    int node = node0 + t;
    if (node < n) {
        rowPtr[node] = s0 + excl;
        dinv[node] = rsqrtf((float)v + 1.0f);   // +1 self-loop
    }
    cur[t] = excl;
    __syncthreads();
    if (len <= SEGCAP) {
        for (int i = s0 + t; i < s1; i += 256) {
            unsigned long long p = tmp[i];
            int c = (int)(p >> 32);
            int r = (int)(p & 0xffffffffu);
            int pos = atomicAdd(&cur[c - node0], 1);
            seg[pos] = r;
        }
        __syncthreads();
        for (int i = t; i < len; i += 256)
            srcList[s0 + i] = seg[i];
    } else {                                    // overflow fallback (never for this graph)
        for (int i = s0 + t; i < s1; i += 256) {
            unsigned long long p = tmp[i];
            int c = (int)(p >> 32);
            int r = (int)(p & 0xffffffffu);
            int pos = atomicAdd(&cur[c - node0], 1);
            srcList[s0 + pos] = r;
        }
    }
}

// ---------------------------------------------------------------------------
// pack_w: W f32 [k][n] (128x128) -> MFMA B-fragment-ordered bf16 hi/lo planes.
// Wp[plane][kb][jt][lane][i] ; element = W[kb*32 + (lane>>4)*8 + i][jt*16 + (lane&15)]
// ---------------------------------------------------------------------------
__global__ __launch_bounds__(256) void pack_w(const float* __restrict__ W,
                                              unsigned short* __restrict__ Wp) {
    int t = threadIdx.x;
    for (int s = t; s < 16384; s += 256) {
        int i = s & 7;
        int lane = (s >> 3) & 63;
        int jt = (s >> 9) & 7;
        int kb = s >> 12;
        int k = kb * 32 + ((lane >> 4) & 3) * 8 + i;
        int nn = jt * 16 + (lane & 15);
        float v = W[k * 128 + nn];
        __hip_bfloat16 hi = __float2bfloat16(v);
        float hf = __bfloat162float(hi);
        __hip_bfloat16 lo = __float2bfloat16(v - hf);
        Wp[s]         = *(unsigned short*)&hi;
        Wp[16384 + s] = *(unsigned short*)&lo;
    }
}

// ---------------------------------------------------------------------------
// cast_hilo: f32 -> bf16 hi/lo planes (row-major [n][128]).
// ---------------------------------------------------------------------------
__global__ __launch_bounds__(256) void cast_hilo(const float* __restrict__ x,
                                                 unsigned short* __restrict__ hi,
                                                 unsigned short* __restrict__ lo,
                                                 int total4) {
    int i = blockIdx.x * 256 + threadIdx.x;
    if (i >= total4) return;
    float4 v = ((const float4*)x)[i];
    ushort4 h, l;
    __hip_bfloat16 b;
    float f;
    b = __float2bfloat16(v.x); f = __bfloat162float(b); h.x = *(unsigned short*)&b;
    b = __float2bfloat16(v.x - f); l.x = *(unsigned short*)&b;
    b = __float2bfloat16(v.y); f = __bfloat162float(b); h.y = *(unsigned short*)&b;
    b = __float2bfloat16(v.y - f); l.y = *(unsigned short*)&b;
    b = __float2bfloat16(v.z); f = __bfloat162float(b); h.z = *(unsigned short*)&b;
    b = __float2bfloat16(v.z - f); l.z = *(unsigned short*)&b;
    b = __float2bfloat16(v.w); f = __bfloat162float(b); h.w = *(unsigned short*)&b;
    b = __float2bfloat16(v.w - f); l.w = *(unsigned short*)&b;
    ((ushort4*)hi)[i] = h;
    ((ushort4*)lo)[i] = l;
}

// ---------------------------------------------------------------------------
// MFMA gemm: A (hi/lo bf16 planes [n][128]) @ W (packed) -> hb bf16 = C*dinv.
// 256 threads = 4 waves; wave = 16 output rows x 128 cols; K=128 = 4 ksteps.
// 3 MFMA per (kb,jt): ah*bh + ah*bl + al*bh  (~f32 precision).
// ---------------------------------------------------------------------------
__global__ __launch_bounds__(256) void gemm_mfma(const unsigned short* __restrict__ Ahi,
                                                 const unsigned short* __restrict__ Alo,
                                                 const unsigned short* __restrict__ Wp,
                                                 const float* __restrict__ dinv,
                                                 unsigned short* __restrict__ hbOut,
                                                 int n) {
    const int tx = threadIdx.x;
    const int wv = tx >> 6;
    const int l  = tx & 63;
    const int m0 = blockIdx.x * 64 + wv * 16;
    int arow = m0 + (l & 15);
    if (arow >= n) arow = 0;            // clamped rows only affect unstored outputs
    const int kofs = (l >> 4) * 8;

    f32x4v acc[8];
#pragma unroll
    for (int jt = 0; jt < 8; jt++) acc[jt] = (f32x4v){0.f, 0.f, 0.f, 0.f};

#pragma unroll
    for (int kb = 0; kb < 4; kb++) {
        bf16x8v ah = *(const bf16x8v*)(Ahi + (size_t)arow * 128 + kb * 32 + kofs);
        bf16x8v al = *(const bf16x8v*)(Alo + (size_t)arow * 128 + kb * 32 + kofs);
        const unsigned short* wb = Wp + (kb * 8) * 512 + l * 8;
#pragma unroll
        for (int jt = 0; jt < 8; jt++) {
            bf16x8v bh = *(const bf16x8v*)(wb + jt * 512);
            bf16x8v bl = *(const bf16x8v*)(wb + jt * 512 + 16384);
            acc[jt] = __builtin_amdgcn_mfma_f32_16x16x32_bf16(ah, bh, acc[jt], 0, 0, 0);
            acc[jt] = __builtin_amdgcn_mfma_f32_16x16x32_bf16(ah, bl, acc[jt], 0, 0, 0);
            acc[jt] = __builtin_amdgcn_mfma_f32_16x16x32_bf16(al, bh, acc[jt], 0, 0, 0);
        }
    }

    const int r0 = m0 + (l >> 4) * 4;
    const int colb = l & 15;
#pragma unroll
    for (int r = 0; r < 4; r++) {
        int grow = r0 + r;
        if (grow < n) {
            float dv = dinv[grow];
#pragma unroll
            for (int jt = 0; jt < 8; jt++) {
                __hip_bfloat16 t = __float2bfloat16(acc[jt][r] * dv);
                hbOut[(size_t)grow * 128 + jt * 16 + colb] = *(unsigned short*)&t;
            }
        }
    }
}

#define BF_LO(u) __uint_as_float((u) << 16)
#define BF_HI(u) __uint_as_float((u) & 0xffff0000u)

// ---------------------------------------------------------------------------
// agg_post (LN layers): R28 gather structure; output = hi/lo bf16 planes.
// ---------------------------------------------------------------------------
__global__ __launch_bounds__(128) void agg_post(const unsigned int* __restrict__ hb,
                                                const int* __restrict__ rowPtr,
                                                const int* __restrict__ srcList,
                                                const float* __restrict__ dinv,
                                                const float* __restrict__ b,
                                                const float* __restrict__ g,
                                                const float* __restrict__ beta,
                                                unsigned short* __restrict__ outHi,
                                                unsigned short* __restrict__ outLo,
                                                int n) {
    int wid = (blockIdx.x * 128 + threadIdx.x) >> 6;
    int lane = threadIdx.x & 63;
    if (wid >= n) return;
    int h = lane & 15;
    int gg = lane >> 4;
    int e0 = rowPtr[wid], e1 = rowPtr[wid + 1];
    float dc = dinv[wid];
    const uint4* hb4 = (const uint4*)hb;

    uint4 us = hb4[(size_t)wid * 16 + h];

    float a[8];
#pragma unroll
    for (int j = 0; j < 8; j++) a[j] = 0.f;

    int idx0 = (e0 + gg < e1) ? srcList[e0 + gg] : -1;
    int idx1 = (e0 + 4 + gg < e1) ? srcList[e0 + 4 + gg] : -1;
    int e = e0;
    for (; e + 8 <= e1; e += 8) {
        int ni0 = (e + 8 + gg < e1) ? srcList[e + 8 + gg] : -1;
        int ni1 = (e + 12 + gg < e1) ? srcList[e + 12 + gg] : -1;
        uint4 u0 = hb4[(size_t)idx0 * 16 + h];
        uint4 u1 = hb4[(size_t)idx1 * 16 + h];
        a[0] += BF_LO(u0.x); a[1] += BF_HI(u0.x);
        a[2] += BF_LO(u0.y); a[3] += BF_HI(u0.y);
        a[4] += BF_LO(u0.z); a[5] += BF_HI(u0.z);
        a[6] += BF_LO(u0.w); a[7] += BF_HI(u0.w);
        a[0] += BF_LO(u1.x); a[1] += BF_HI(u1.x);
        a[2] += BF_LO(u1.y); a[3] += BF_HI(u1.y);
        a[4] += BF_LO(u1.z); a[5] += BF_HI(u1.z);
        a[6] += BF_LO(u1.w); a[7] += BF_HI(u1.w);
        idx0 = ni0; idx1 = ni1;
    }
    if (idx0 >= 0) {
        uint4 u = hb4[(size_t)idx0 * 16 + h];
        a[0] += BF_LO(u.x); a[1] += BF_HI(u.x);
        a[2] += BF_LO(u.y); a[3] += BF_HI(u.y);
        a[4] += BF_LO(u.z); a[5] += BF_HI(u.z);
        a[6] += BF_LO(u.w); a[7] += BF_HI(u.w);
    }
    if (idx1 >= 0) {
        uint4 u = hb4[(size_t)idx1 * 16 + h];
        a[0] += BF_LO(u.x); a[1] += BF_HI(u.x);
        a[2] += BF_LO(u.y); a[3] += BF_HI(u.y);
        a[4] += BF_LO(u.z); a[5] += BF_HI(u.z);
        a[6] += BF_LO(u.w); a[7] += BF_HI(u.w);
    }
#pragma unroll
    for (int j = 0; j < 8; j++) {
        a[j] += __shfl_xor(a[j], 16, 64);
        a[j] += __shfl_xor(a[j], 32, 64);
    }
    a[0] += BF_LO(us.x); a[1] += BF_HI(us.x);
    a[2] += BF_LO(us.y); a[3] += BF_HI(us.y);
    a[4] += BF_LO(us.z); a[5] += BF_HI(us.z);
    a[6] += BF_LO(us.w); a[7] += BF_HI(us.w);

    float4 bv0 = *(const float4*)(b + h * 8);
    float4 bv1 = *(const float4*)(b + h * 8 + 4);
    a[0] = fmaxf(a[0] * dc + bv0.x, 0.f);
    a[1] = fmaxf(a[1] * dc + bv0.y, 0.f);
    a[2] = fmaxf(a[2] * dc + bv0.z, 0.f);
    a[3] = fmaxf(a[3] * dc + bv0.w, 0.f);
    a[4] = fmaxf(a[4] * dc + bv1.x, 0.f);
    a[5] = fmaxf(a[5] * dc + bv1.y, 0.f);
    a[6] = fmaxf(a[6] * dc + bv1.z, 0.f);
    a[7] = fmaxf(a[7] * dc + bv1.w, 0.f);

    float s = ((a[0] + a[1]) + (a[2] + a[3])) + ((a[4] + a[5]) + (a[6] + a[7]));
#pragma unroll
    for (int m = 8; m >= 1; m >>= 1) s += __shfl_xor(s, m, 64);
    float mu = s * (1.f / 128.f);
    float sq = 0.f;
    float d[8];
#pragma unroll
    for (int j = 0; j < 8; j++) { d[j] = a[j] - mu; sq += d[j] * d[j]; }
#pragma unroll
    for (int m = 8; m >= 1; m >>= 1) sq += __shfl_xor(sq, m, 64);
    float rs = rsqrtf(sq * (1.f / 128.f) + EPS_LN);
    float4 gv0 = *(const float4*)(g + h * 8);
    float4 gv1 = *(const float4*)(g + h * 8 + 4);
    float4 bt0 = *(const float4*)(beta + h * 8);
    float4 bt1 = *(const float4*)(beta + h * 8 + 4);
    a[0] = d[0] * rs * gv0.x + bt0.x;
    a[1] = d[1] * rs * gv0.y + bt0.y;
    a[2] = d[2] * rs * gv0.z + bt0.z;
    a[3] = d[3] * rs * gv0.w + bt0.w;
    a[4] = d[4] * rs * gv1.x + bt1.x;
    a[5] = d[5] * rs * gv1.y + bt1.y;
    a[6] = d[6] * rs * gv1.z + bt1.z;
    a[7] = d[7] * rs * gv1.w + bt1.w;

    if (gg == 0) {
        ushort4 h0, h1, l0, l1;
        __hip_bfloat16 bb; float ff;
        bb = __float2bfloat16(a[0]); ff = __bfloat162float(bb); h0.x = *(unsigned short*)&bb;
        bb = __float2bfloat16(a[0] - ff); l0.x = *(unsigned short*)&bb;
        bb = __float2bfloat16(a[1]); ff = __bfloat162float(bb); h0.y = *(unsigned short*)&bb;
        bb = __float2bfloat16(a[1] - ff); l0.y = *(unsigned short*)&bb;
        bb = __float2bfloat16(a[2]); ff = __bfloat162float(bb); h0.z = *(unsigned short*)&bb;
        bb = __float2bfloat16(a[2] - ff); l0.z = *(unsigned short*)&bb;
        bb = __float2bfloat16(a[3]); ff = __bfloat162float(bb); h0.w = *(unsigned short*)&bb;
        bb = __float2bfloat16(a[3] - ff); l0.w = *(unsigned short*)&bb;
        bb = __float2bfloat16(a[4]); ff = __bfloat162float(bb); h1.x = *(unsigned short*)&bb;
        bb = __float2bfloat16(a[4] - ff); l1.x = *(unsigned short*)&bb;
        bb = __float2bfloat16(a[5]); ff = __bfloat162float(bb); h1.y = *(unsigned short*)&bb;
        bb = __float2bfloat16(a[5] - ff); l1.y = *(unsigned short*)&bb;
        bb = __float2bfloat16(a[6]); ff = __bfloat162float(bb); h1.z = *(unsigned short*)&bb;
        bb = __float2bfloat16(a[6] - ff); l1.z = *(unsigned short*)&bb;
        bb = __float2bfloat16(a[7]); ff = __bfloat162float(bb); h1.w = *(unsigned short*)&bb;
        bb = __float2bfloat16(a[7] - ff); l1.w = *(unsigned short*)&bb;
        size_t base = (size_t)wid * 128 + h * 8;
        *(ushort4*)(outHi + base)     = h0;
        *(ushort4*)(outHi + base + 4) = h1;
        *(ushort4*)(outLo + base)     = l0;
        *(ushort4*)(outLo + base + 4) = l1;
    }
}

// ---------------------------------------------------------------------------
// Fused layer-3 agg (relu, no LN) + collapsed head: out = h @ Weff + beff.
// ---------------------------------------------------------------------------
__global__ __launch_bounds__(128) void agg_head(
        const unsigned int* __restrict__ hb,
        const int* __restrict__ rowPtr,
        const int* __restrict__ srcList,
        const float* __restrict__ dinv,
        const float* __restrict__ b,
        const float* __restrict__ Weff,
        const float* __restrict__ beff,
        float* __restrict__ out, int n) {
    __shared__ float Wl[384];
    int tt = threadIdx.x;
    Wl[tt] = Weff[tt]; Wl[tt + 128] = Weff[tt + 128]; Wl[tt + 256] = Weff[tt + 256];
    __syncthreads();

    int wid = (blockIdx.x * 128 + tt) >> 6;
    int lane = tt & 63;
    if (wid >= n) return;
    int h = lane & 15;
    int gg = lane >> 4;
    int e0 = rowPtr[wid], e1 = rowPtr[wid + 1];
    float dc = dinv[wid];
    const uint4* hb4 = (const uint4*)hb;
    uint4 us = hb4[(size_t)wid * 16 + h];

    float a[8];
#pragma unroll
    for (int j = 0; j < 8; j++) a[j] = 0.f;

    int idx0 = (e0 + gg < e1) ? srcList[e0 + gg] : -1;
    int idx1 = (e0 + 4 + gg < e1) ? srcList[e0 + 4 + gg] : -1;
    int e = e0;
    for (; e + 8 <= e1; e += 8) {
        int ni0 = (e + 8 + gg < e1) ? srcList[e + 8 + gg] : -1;
        int ni1 = (e + 12 + gg < e1) ? srcList[e + 12 + gg] : -1;
        uint4 u0 = hb4[(size_t)idx0 * 16 + h];
        uint4 u1 = hb4[(size_t)idx1 * 16 + h];
        a[0] += BF_LO(u0.x); a[1] += BF_HI(u0.x);
        a[2] += BF_LO(u0.y); a[3] += BF_HI(u0.y);
        a[4] += BF_LO(u0.z); a[5] += BF_HI(u0.z);
        a[6] += BF_LO(u0.w); a[7] += BF_HI(u0.w);
        a[0] += BF_LO(u1.x); a[1] += BF_HI(u1.x);
        a[2] += BF_LO(u1.y); a[3] += BF_HI(u1.y);
        a[4] += BF_LO(u1.z); a[5] += BF_HI(u1.z);
        a[6] += BF_LO(u1.w); a[7] += BF_HI(u1.w);
        idx0 = ni0; idx1 = ni1;
    }
    if (idx0 >= 0) {
        uint4 u = hb4[(size_t)idx0 * 16 + h];
        a[0] += BF_LO(u.x); a[1] += BF_HI(u.x);
        a[2] += BF_LO(u.y); a[3] += BF_HI(u.y);
        a[4] += BF_LO(u.z); a[5] += BF_HI(u.z);
        a[6] += BF_LO(u.w); a[7] += BF_HI(u.w);
    }
    if (idx1 >= 0) {
        uint4 u = hb4[(size_t)idx1 * 16 + h];
        a[0] += BF_LO(u.x); a[1] += BF_HI(u.x);
        a[2] += BF_LO(u.y); a[3] += BF_HI(u.y);
        a[4] += BF_LO(u.z); a[5] += BF_HI(u.z);
        a[6] += BF_LO(u.w); a[7] += BF_HI(u.w);
    }
#pragma unroll
    for (int j = 0; j < 8; j++) {
        a[j] += __shfl_xor(a[j], 16, 64);
        a[j] += __shfl_xor(a[j], 32, 64);
    }
    a[0] += BF_LO(us.x); a[1] += BF_HI(us.x);
    a[2] += BF_LO(us.y); a[3] += BF_HI(us.y);
    a[4] += BF_LO(us.z); a[5] += BF_HI(us.z);
    a[6] += BF_LO(us.w); a[7] += BF_HI(us.w);

    float4 bv0 = *(const float4*)(b + h * 8);
    float4 bv1 = *(const float4*)(b + h * 8 + 4);
    a[0] = fmaxf(a[0] * dc + bv0.x, 0.f);
    a[1] = fmaxf(a[1] * dc + bv0.y, 0.f);
    a[2] = fmaxf(a[2] * dc + bv0.z, 0.f);
    a[3] = fmaxf(a[3] * dc + bv0.w, 0.f);
    a[4] = fmaxf(a[4] * dc + bv1.x, 0.f);
    a[5] = fmaxf(a[5] * dc + bv1.y, 0.f);
    a[6] = fmaxf(a[6] * dc + bv1.z, 0.f);
    a[7] = fmaxf(a[7] * dc + bv1.w, 0.f);

    float p0 = 0.f, p1 = 0.f, p2 = 0.f;
#pragma unroll
    for (int j = 0; j < 8; j++) {
        const float* w = &Wl[(8 * h + j) * 3];
        p0 += a[j] * w[0];
        p1 += a[j] * w[1];
        p2 += a[j] * w[2];
    }
#pragma unroll
    for (int m = 8; m >= 1; m >>= 1) {
        p0 += __shfl_xor(p0, m, 64);
        p1 += __shfl_xor(p1, m, 64);
        p2 += __shfl_xor(p2, m, 64);
    }
    if (lane == 0) {
        out[(size_t)wid * 3 + 0] = p0 + beff[0];
        out[(size_t)wid * 3 + 1] = p1 + beff[1];
        out[(size_t)wid * 3 + 2] = p2 + beff[2];
    }
}

// ---------------------------------------------------------------------------
// Head collapse: Weff = Wp1 @ Wp2 (128x3), beff = bp1 @ Wp2 + bp2.
// ---------------------------------------------------------------------------
__global__ __launch_bounds__(128) void head_collapse(const float* __restrict__ Wp1,
                                                     const float* __restrict__ bp1,
                                                     const float* __restrict__ Wp2,
                                                     const float* __restrict__ bp2,
                                                     float* __restrict__ Weff,
                                                     float* __restrict__ beff) {
    __shared__ float w2[384];
    int t = threadIdx.x;
    w2[t] = Wp2[t]; w2[t + 128] = Wp2[t + 128]; w2[t + 256] = Wp2[t + 256];
    __syncthreads();
    float p0 = 0.f, p1 = 0.f, p2 = 0.f;
    const float* wr = Wp1 + (size_t)t * 128;
    for (int k = 0; k < 128; k++) {
        float v = wr[k];
        p0 += v * w2[k * 3 + 0];
        p1 += v * w2[k * 3 + 1];
        p2 += v * w2[k * 3 + 2];
    }
    Weff[t * 3 + 0] = p0; Weff[t * 3 + 1] = p1; Weff[t * 3 + 2] = p2;
    if (t == 0) {
        float q0 = bp2[0], q1 = bp2[1], q2 = bp2[2];
        for (int k = 0; k < 128; k++) {
            float v = bp1[k];
            q0 += v * w2[k * 3 + 0];
            q1 += v * w2[k * 3 + 1];
            q2 += v * w2[k * 3 + 2];
        }
        beff[0] = q0; beff[1] = q1; beff[2] = q2;
    }
}

// ---------------------------------------------------------------------------
extern "C" void kernel_launch(void* const* d_in, const int* in_sizes, int n_in,
                              void* d_out, int out_size, void* d_ws, size_t ws_size,
                              hipStream_t stream) {
    const float* x   = (const float*)d_in[0];
    const int* ei    = (const int*)d_in[1];
    const float* W1  = (const float*)d_in[2];
    const float* b1  = (const float*)d_in[3];
    const float* W2  = (const float*)d_in[4];
    const float* b2  = (const float*)d_in[5];
    const float* W3  = (const float*)d_in[6];
    const float* b3  = (const float*)d_in[7];
    const float* g1  = (const float*)d_in[8];
    const float* be1 = (const float*)d_in[9];
    const float* g2  = (const float*)d_in[10];
    const float* be2 = (const float*)d_in[11];
    const float* Wp1f = (const float*)d_in[12];
    const float* bp1 = (const float*)d_in[13];
    const float* Wp2f = (const float*)d_in[14];
    const float* bp2 = (const float*)d_in[15];
    float* out = (float*)d_out;

    const int n = in_sizes[0] / 128;   // 50000
    const int E = in_sizes[1] / 2;     // 1600000
    const int* row = ei;
    const int* col = ei + E;

    char* ws = (char*)d_ws;
    size_t nA  = ((size_t)n * 4 + 255) & ~(size_t)255;
    size_t nA1 = ((size_t)(n + 1) * 4 + 255) & ~(size_t)255;
    size_t eA  = ((size_t)E * 4 + 255) & ~(size_t)255;
    size_t hbSz = ((size_t)n * 128 * 2 + 255) & ~(size_t)255;
    int*   rowPtr  = (int*)ws;
    float* dinvp   = (float*)(ws + nA1);
    int*   srcList = (int*)(ws + nA1 + nA);
    unsigned short* hbA = (unsigned short*)(ws + nA1 + nA + eA);
    unsigned short* hbB = hbA + hbSz / 2;
    unsigned short* Phi = hbB + hbSz / 2;
    unsigned short* Plo = Phi + hbSz / 2;
    unsigned short* Wq1 = Plo + hbSz / 2;
    unsigned short* Wq2 = Wq1 + 32768;
    unsigned short* Wq3 = Wq2 + 32768;
    float* Weff = (float*)(Wq3 + 32768);
    float* beff = Weff + 384;
    // CSR scratch aliases Phi/Plo (consumed by bucket_fill before cast_hilo):
    unsigned long long* tmp = (unsigned long long*)Phi;
    int* chunkBH     = (int*)((char*)Phi + 2 * eA);
    int* bucketStart = (int*)((char*)Phi + 2 * eA + (size_t)NB * 256 * 4);

    const int nbuck = (n + 255) >> 8;                 // 196
    const int per   = (((E + NB - 1) / NB) + 15) & ~15;
    const int tileBlocks = (n + 63) / 64;             // 782
    const int nodeWaveBlocks = (n + 1) / 2;           // 25000
    const int castBlocks = (n * 128 / 4 + 255) / 256;

    // CSR build (bucketed counting sort, zero global atomics)
    bucket_hist<<<NB, 256, 0, stream>>>(col, chunkBH, E, per, nbuck);
    bucket_scan<<<1, 256, 0, stream>>>(chunkBH, bucketStart, rowPtr, E, n, nbuck, NB);
    scatter_pairs<<<NB, 256, 0, stream>>>(row, col, chunkBH, bucketStart, tmp, E, per, nbuck);
    bucket_fill<<<nbuck, 256, 0, stream>>>(tmp, bucketStart, rowPtr, dinvp, srcList, n);
    head_collapse<<<1, 128, 0, stream>>>(Wp1f, bp1, Wp2f, bp2, Weff, beff);
    pack_w<<<1, 256, 0, stream>>>(W1, Wq1);
    pack_w<<<1, 256, 0, stream>>>(W2, Wq2);
    pack_w<<<1, 256, 0, stream>>>(W3, Wq3);

    // x -> hi/lo planes (reuses Phi/Plo after CSR scratch dies)
    cast_hilo<<<castBlocks, 256, 0, stream>>>(x, Phi, Plo, n * 128 / 4);

    // ---- layer 1 ----
    gemm_mfma<<<tileBlocks, 256, 0, stream>>>(Phi, Plo, Wq1, dinvp, hbA, n);
    agg_post<<<nodeWaveBlocks, 128, 0, stream>>>((const unsigned int*)hbA,
                                                 rowPtr, srcList, dinvp,
                                                 b1, g1, be1, Phi, Plo, n);
    // ---- layer 2 ----
    gemm_mfma<<<tileBlocks, 256, 0, stream>>>(Phi, Plo, Wq2, dinvp, hbB, n);
    agg_post<<<nodeWaveBlocks, 128, 0, stream>>>((const unsigned int*)hbB,
                                                 rowPtr, srcList, dinvp,
                                                 b2, g2, be2, Phi, Plo, n);
    // ---- layer 3 ----
    gemm_mfma<<<tileBlocks, 256, 0, stream>>>(Phi, Plo, Wq3, dinvp, hbA, n);
    agg_head<<<nodeWaveBlocks, 128, 0, stream>>>((const unsigned int*)hbA,
                                                 rowPtr, srcList, dinvp,
                                                 b3, Weff, beff, out, n);
}

// Round 11
// 364.288 us; speedup vs baseline: 1.2817x; 1.1373x over previous
//
#include <hip/hip_runtime.h>
#include <hip/hip_bf16.h>

#define EPS_LN 1e-5f
#define NB    256             // edge chunks for hist/scatter
#define SEGCAP 16384          // srcList segment capacity per bucket (64KB LDS)

typedef int ivec4 __attribute__((ext_vector_type(4)));
typedef short bf16x8v __attribute__((ext_vector_type(8)));
typedef float f32x4v __attribute__((ext_vector_type(4)));
typedef unsigned short u16x8 __attribute__((ext_vector_type(8)));

// ===========================================================================
// R31: consolidate flat costs on R30 (414us, MFMA gemm verified).
//  - gemm: stage packed W in LDS (16KB/kb-slice, loaded once per block) —
//    kills the 400MB of per-wave L2 B-re-reads (~12us/gemm floor).
//  - layer-1 gemm reads x f32 directly, hi/lo split in-register ->
//    cast_hilo kernel deleted (-51MB traffic, -1 launch).
//  - pack_w_all: one 192-block launch replaces 3 serial 1-block launches.
//  - agg_head Wl layout [(j*3+c)*16+h]: lanes read consecutive -> 0 conflicts
//    (was 3.2M, stride-24 4-way).
// Everything else identical to R30.
// ===========================================================================

__global__ __launch_bounds__(256) void bucket_hist(const int* __restrict__ col,
                                                   int* __restrict__ chunkBH,
                                                   int E, int per, int nbuck) {
    __shared__ int hist[256];
    int t = threadIdx.x;
    hist[t] = 0;
    __syncthreads();
    int s0 = blockIdx.x * per;
    int s1 = s0 + per; if (s1 > E) s1 = E;
    if (s0 < s1) {
        int q0 = s0 >> 2, q1 = s1 >> 2;
        for (int i = q0 + t; i < q1; i += 256) {
            ivec4 c = __builtin_nontemporal_load((const ivec4*)col + i);
            atomicAdd(&hist[c.x >> 8], 1);
            atomicAdd(&hist[c.y >> 8], 1);
            atomicAdd(&hist[c.z >> 8], 1);
            atomicAdd(&hist[c.w >> 8], 1);
        }
        for (int i = (q1 << 2) + t; i < s1; i += 256)
            atomicAdd(&hist[col[i] >> 8], 1);
    }
    __syncthreads();
    if (t < nbuck) chunkBH[blockIdx.x * 256 + t] = hist[t];   // [k][b], coalesced
}

__global__ __launch_bounds__(256) void bucket_scan(int* __restrict__ chunkBH,
                                                   int* __restrict__ bucketStart,
                                                   int* __restrict__ rowPtr,
                                                   int E, int n, int nbuck, int nb) {
    __shared__ int tot[256];
    int t = threadIdx.x;
    int run = 0;
    if (t < nbuck) {
        for (int k0 = 0; k0 < nb; k0 += 16) {
            int v[16];
#pragma unroll
            for (int j = 0; j < 16; j++)
                v[j] = (k0 + j < nb) ? chunkBH[(k0 + j) * 256 + t] : 0;
#pragma unroll
            for (int j = 0; j < 16; j++) {
                int tv = v[j];
                if (k0 + j < nb) chunkBH[(k0 + j) * 256 + t] = run;
                run += tv;
            }
        }
    }
    tot[t] = run;
    __syncthreads();
    for (int d = 1; d < 256; d <<= 1) {
        int add = (t >= d) ? tot[t - d] : 0;
        __syncthreads();
        tot[t] += add;
        __syncthreads();
    }
    if (t < nbuck) bucketStart[t] = tot[t] - run;
    if (t == 0) { bucketStart[nbuck] = E; rowPtr[n] = E; }
}

__global__ __launch_bounds__(256) void scatter_pairs(const int* __restrict__ row,
                                                     const int* __restrict__ col,
                                                     const int* __restrict__ chunkBH,
                                                     const int* __restrict__ bucketStart,
                                                     unsigned long long* __restrict__ tmp,
                                                     int E, int per, int nbuck) {
    __shared__ int curs[256];
    int t = threadIdx.x;
    int k = blockIdx.x;
    curs[t] = (t < nbuck) ? (chunkBH[k * 256 + t] + bucketStart[t]) : 0;
    __syncthreads();
    int s0 = k * per;
    int s1 = s0 + per; if (s1 > E) s1 = E;
    if (s0 >= s1) return;
    int q0 = s0 >> 2, q1 = s1 >> 2;
    for (int i = q0 + t; i < q1; i += 256) {
        ivec4 c4 = __builtin_nontemporal_load((const ivec4*)col + i);
        ivec4 r4 = __builtin_nontemporal_load((const ivec4*)row + i);
        int p0 = atomicAdd(&curs[c4.x >> 8], 1);
        tmp[p0] = ((unsigned long long)(unsigned)c4.x << 32) | (unsigned)r4.x;
        int p1 = atomicAdd(&curs[c4.y >> 8], 1);
        tmp[p1] = ((unsigned long long)(unsigned)c4.y << 32) | (unsigned)r4.y;
        int p2 = atomicAdd(&curs[c4.z >> 8], 1);
        tmp[p2] = ((unsigned long long)(unsigned)c4.z << 32) | (unsigned)r4.z;
        int p3 = atomicAdd(&curs[c4.w >> 8], 1);
        tmp[p3] = ((unsigned long long)(unsigned)c4.w << 32) | (unsigned)r4.w;
    }
    for (int i = (q1 << 2) + t; i < s1; i += 256) {
        int c = col[i], r = row[i];
        int p = atomicAdd(&curs[c >> 8], 1);
        tmp[p] = ((unsigned long long)(unsigned)c << 32) | (unsigned)r;
    }
}

__global__ __launch_bounds__(256) void bucket_fill(const unsigned long long* __restrict__ tmp,
                                                   const int* __restrict__ bucketStart,
                                                   int* __restrict__ rowPtr,
                                                   float* __restrict__ dinv,
                                                   int* __restrict__ srcList,
                                                   int n) {
    __shared__ int cnt[256];
    __shared__ int cur[256];
    __shared__ int seg[SEGCAP];
    int b = blockIdx.x, t = threadIdx.x;
    int node0 = b << 8;
    int s0 = bucketStart[b], s1 = bucketStart[b + 1];
    int len = s1 - s0;
    cnt[t] = 0;
    __syncthreads();
    for (int i = s0 + t; i < s1; i += 256) {
        int c = (int)(tmp[i] >> 32);
        atomicAdd(&cnt[c - node0], 1);
    }
    __syncthreads();
    int v = cnt[t];
    cur[t] = v;
    __syncthreads();
    for (int d = 1; d < 256; d <<= 1) {
        int add = (t >= d) ? cur[t - d] : 0;
        __syncthreads();
        cur[t] += add;
        __syncthreads();
    }
    int excl = cur[t] - v;
    int node = node0 + t;
    if (node < n) {
        rowPtr[node] = s0 + excl;
        dinv[node] = rsqrtf((float)v + 1.0f);   // +1 self-loop
    }
    cur[t] = excl;
    __syncthreads();
    if (len <= SEGCAP) {
        for (int i = s0 + t; i < s1; i += 256) {
            unsigned long long p = tmp[i];
            int c = (int)(p >> 32);
            int r = (int)(p & 0xffffffffu);
            int pos = atomicAdd(&cur[c - node0], 1);
            seg[pos] = r;
        }
        __syncthreads();
        for (int i = t; i < len; i += 256)
            srcList[s0 + i] = seg[i];
    } else {                                    // overflow fallback (never for this graph)
        for (int i = s0 + t; i < s1; i += 256) {
            unsigned long long p = tmp[i];
            int c = (int)(p >> 32);
            int r = (int)(p & 0xffffffffu);
            int pos = atomicAdd(&cur[c - node0], 1);
            srcList[s0 + pos] = r;
        }
    }
}

// ---------------------------------------------------------------------------
// pack_w_all: 3 weights -> MFMA B-fragment-ordered bf16 hi/lo planes.
// Grid = 3*64 blocks; block handles 256 elements of one weight.
// Wp[plane][kb][jt][lane][i]; element = W[kb*32+(lane>>4)*8+i][jt*16+(lane&15)]
// ---------------------------------------------------------------------------
__global__ __launch_bounds__(256) void pack_w_all(const float* __restrict__ W1,
                                                  const float* __restrict__ W2,
                                                  const float* __restrict__ W3,
                                                  unsigned short* __restrict__ Wq) {
    int w = blockIdx.x >> 6;
    const float* W = (w == 0) ? W1 : (w == 1) ? W2 : W3;
    unsigned short* Wp = Wq + (size_t)w * 32768;
    int s = (blockIdx.x & 63) * 256 + threadIdx.x;   // 0..16383
    int i = s & 7;
    int lane = (s >> 3) & 63;
    int jt = (s >> 9) & 7;
    int kb = s >> 12;
    int k = kb * 32 + ((lane >> 4) & 3) * 8 + i;
    int nn = jt * 16 + (lane & 15);
    float v = W[k * 128 + nn];
    __hip_bfloat16 hi = __float2bfloat16(v);
    float hf = __bfloat162float(hi);
    __hip_bfloat16 lo = __float2bfloat16(v - hf);
    Wp[s]         = *(unsigned short*)&hi;
    Wp[16384 + s] = *(unsigned short*)&lo;
}

// ---------------------------------------------------------------------------
// MFMA gemm core. B staged in LDS per kb-slice (16KB), loaded once per block.
// 256 threads = 4 waves; wave = 16 output rows x 128 cols; K=128 = 4 ksteps.
// 3 MFMA per (kb,jt): ah*bh + ah*bl + al*bh (~f32 precision).
// ---------------------------------------------------------------------------
__device__ __forceinline__ void split8(const float* __restrict__ p,
                                       bf16x8v& ah, bf16x8v& al) {
#pragma unroll
    for (int i = 0; i < 8; i++) {
        float v = p[i];
        __hip_bfloat16 hb = __float2bfloat16(v);
        float hf = __bfloat162float(hb);
        __hip_bfloat16 lb = __float2bfloat16(v - hf);
        ah[i] = *(short*)&hb;
        al[i] = *(short*)&lb;
    }
}

template<int ASRC>   // 0: f32 A (split in-register), 1: hi/lo bf16 planes
__global__ __launch_bounds__(256) void gemm_mfma(const float* __restrict__ Af32,
                                                 const unsigned short* __restrict__ Ahi,
                                                 const unsigned short* __restrict__ Alo,
                                                 const unsigned short* __restrict__ Wp,
                                                 const float* __restrict__ dinv,
                                                 unsigned short* __restrict__ hbOut,
                                                 int n) {
    __shared__ unsigned short Bs[8192];   // hi[4096] || lo[4096] for one kb-slice

    const int tx = threadIdx.x;
    const int wv = tx >> 6;
    const int l  = tx & 63;
    const int m0 = blockIdx.x * 64 + wv * 16;
    int arow = m0 + (l & 15);
    if (arow >= n) arow = 0;            // clamped rows only affect unstored outputs
    const int kofs = (l >> 4) * 8;

    f32x4v acc[8];
#pragma unroll
    for (int jt = 0; jt < 8; jt++) acc[jt] = (f32x4v){0.f, 0.f, 0.f, 0.f};

#pragma unroll
    for (int kb = 0; kb < 4; kb++) {
        __syncthreads();   // protect previous slice's reads
        {   // stage 4096 hi + 4096 lo ushorts: 16+16 per thread
            u16x8* dH = (u16x8*)&Bs[tx * 16];
            const u16x8* sH = (const u16x8*)(Wp + kb * 4096 + tx * 16);
            dH[0] = sH[0]; dH[1] = sH[1];
            u16x8* dL = (u16x8*)&Bs[4096 + tx * 16];
            const u16x8* sL = (const u16x8*)(Wp + 16384 + kb * 4096 + tx * 16);
            dL[0] = sL[0]; dL[1] = sL[1];
        }
        bf16x8v ah, al;
        if (ASRC == 0) {
            split8(Af32 + (size_t)arow * 128 + kb * 32 + kofs, ah, al);
        } else {
            ah = *(const bf16x8v*)(Ahi + (size_t)arow * 128 + kb * 32 + kofs);
            al = *(const bf16x8v*)(Alo + (size_t)arow * 128 + kb * 32 + kofs);
        }
        __syncthreads();
#pragma unroll
        for (int jt = 0; jt < 8; jt++) {
            bf16x8v bh = *(const bf16x8v*)&Bs[jt * 512 + l * 8];
            bf16x8v bl = *(const bf16x8v*)&Bs[4096 + jt * 512 + l * 8];
            acc[jt] = __builtin_amdgcn_mfma_f32_16x16x32_bf16(ah, bh, acc[jt], 0, 0, 0);
            acc[jt] = __builtin_amdgcn_mfma_f32_16x16x32_bf16(ah, bl, acc[jt], 0, 0, 0);
            acc[jt] = __builtin_amdgcn_mfma_f32_16x16x32_bf16(al, bh, acc[jt], 0, 0, 0);
        }
    }

    const int r0 = m0 + (l >> 4) * 4;
    const int colb = l & 15;
#pragma unroll
    for (int r = 0; r < 4; r++) {
        int grow = r0 + r;
        if (grow < n) {
            float dv = dinv[grow];
#pragma unroll
            for (int jt = 0; jt < 8; jt++) {
                __hip_bfloat16 t = __float2bfloat16(acc[jt][r] * dv);
                hbOut[(size_t)grow * 128 + jt * 16 + colb] = *(unsigned short*)&t;
            }
        }
    }
}

#define BF_LO(u) __uint_as_float((u) << 16)
#define BF_HI(u) __uint_as_float((u) & 0xffff0000u)

// ---------------------------------------------------------------------------
// agg_post (LN layers): R28 gather structure; output = hi/lo bf16 planes.
// ---------------------------------------------------------------------------
__global__ __launch_bounds__(128) void agg_post(const unsigned int* __restrict__ hb,
                                                const int* __restrict__ rowPtr,
                                                const int* __restrict__ srcList,
                                                const float* __restrict__ dinv,
                                                const float* __restrict__ b,
                                                const float* __restrict__ g,
                                                const float* __restrict__ beta,
                                                unsigned short* __restrict__ outHi,
                                                unsigned short* __restrict__ outLo,
                                                int n) {
    int wid = (blockIdx.x * 128 + threadIdx.x) >> 6;
    int lane = threadIdx.x & 63;
    if (wid >= n) return;
    int h = lane & 15;
    int gg = lane >> 4;
    int e0 = rowPtr[wid], e1 = rowPtr[wid + 1];
    float dc = dinv[wid];
    const uint4* hb4 = (const uint4*)hb;

    uint4 us = hb4[(size_t)wid * 16 + h];

    float a[8];
#pragma unroll
    for (int j = 0; j < 8; j++) a[j] = 0.f;

    int idx0 = (e0 + gg < e1) ? srcList[e0 + gg] : -1;
    int idx1 = (e0 + 4 + gg < e1) ? srcList[e0 + 4 + gg] : -1;
    int e = e0;
    for (; e + 8 <= e1; e += 8) {
        int ni0 = (e + 8 + gg < e1) ? srcList[e + 8 + gg] : -1;
        int ni1 = (e + 12 + gg < e1) ? srcList[e + 12 + gg] : -1;
        uint4 u0 = hb4[(size_t)idx0 * 16 + h];
        uint4 u1 = hb4[(size_t)idx1 * 16 + h];
        a[0] += BF_LO(u0.x); a[1] += BF_HI(u0.x);
        a[2] += BF_LO(u0.y); a[3] += BF_HI(u0.y);
        a[4] += BF_LO(u0.z); a[5] += BF_HI(u0.z);
        a[6] += BF_LO(u0.w); a[7] += BF_HI(u0.w);
        a[0] += BF_LO(u1.x); a[1] += BF_HI(u1.x);
        a[2] += BF_LO(u1.y); a[3] += BF_HI(u1.y);
        a[4] += BF_LO(u1.z); a[5] += BF_HI(u1.z);
        a[6] += BF_LO(u1.w); a[7] += BF_HI(u1.w);
        idx0 = ni0; idx1 = ni1;
    }
    if (idx0 >= 0) {
        uint4 u = hb4[(size_t)idx0 * 16 + h];
        a[0] += BF_LO(u.x); a[1] += BF_HI(u.x);
        a[2] += BF_LO(u.y); a[3] += BF_HI(u.y);
        a[4] += BF_LO(u.z); a[5] += BF_HI(u.z);
        a[6] += BF_LO(u.w); a[7] += BF_HI(u.w);
    }
    if (idx1 >= 0) {
        uint4 u = hb4[(size_t)idx1 * 16 + h];
        a[0] += BF_LO(u.x); a[1] += BF_HI(u.x);
        a[2] += BF_LO(u.y); a[3] += BF_HI(u.y);
        a[4] += BF_LO(u.z); a[5] += BF_HI(u.z);
        a[6] += BF_LO(u.w); a[7] += BF_HI(u.w);
    }
#pragma unroll
    for (int j = 0; j < 8; j++) {
        a[j] += __shfl_xor(a[j], 16, 64);
        a[j] += __shfl_xor(a[j], 32, 64);
    }
    a[0] += BF_LO(us.x); a[1] += BF_HI(us.x);
    a[2] += BF_LO(us.y); a[3] += BF_HI(us.y);
    a[4] += BF_LO(us.z); a[5] += BF_HI(us.z);
    a[6] += BF_LO(us.w); a[7] += BF_HI(us.w);

    float4 bv0 = *(const float4*)(b + h * 8);
    float4 bv1 = *(const float4*)(b + h * 8 + 4);
    a[0] = fmaxf(a[0] * dc + bv0.x, 0.f);
    a[1] = fmaxf(a[1] * dc + bv0.y, 0.f);
    a[2] = fmaxf(a[2] * dc + bv0.z, 0.f);
    a[3] = fmaxf(a[3] * dc + bv0.w, 0.f);
    a[4] = fmaxf(a[4] * dc + bv1.x, 0.f);
    a[5] = fmaxf(a[5] * dc + bv1.y, 0.f);
    a[6] = fmaxf(a[6] * dc + bv1.z, 0.f);
    a[7] = fmaxf(a[7] * dc + bv1.w, 0.f);

    float s = ((a[0] + a[1]) + (a[2] + a[3])) + ((a[4] + a[5]) + (a[6] + a[7]));
#pragma unroll
    for (int m = 8; m >= 1; m >>= 1) s += __shfl_xor(s, m, 64);
    float mu = s * (1.f / 128.f);
    float sq = 0.f;
    float d[8];
#pragma unroll
    for (int j = 0; j < 8; j++) { d[j] = a[j] - mu; sq += d[j] * d[j]; }
#pragma unroll
    for (int m = 8; m >= 1; m >>= 1) sq += __shfl_xor(sq, m, 64);
    float rs = rsqrtf(sq * (1.f / 128.f) + EPS_LN);
    float4 gv0 = *(const float4*)(g + h * 8);
    float4 gv1 = *(const float4*)(g + h * 8 + 4);
    float4 bt0 = *(const float4*)(beta + h * 8);
    float4 bt1 = *(const float4*)(beta + h * 8 + 4);
    a[0] = d[0] * rs * gv0.x + bt0.x;
    a[1] = d[1] * rs * gv0.y + bt0.y;
    a[2] = d[2] * rs * gv0.z + bt0.z;
    a[3] = d[3] * rs * gv0.w + bt0.w;
    a[4] = d[4] * rs * gv1.x + bt1.x;
    a[5] = d[5] * rs * gv1.y + bt1.y;
    a[6] = d[6] * rs * gv1.z + bt1.z;
    a[7] = d[7] * rs * gv1.w + bt1.w;

    if (gg == 0) {
        ushort4 h0, h1, l0, l1;
        __hip_bfloat16 bb; float ff;
        bb = __float2bfloat16(a[0]); ff = __bfloat162float(bb); h0.x = *(unsigned short*)&bb;
        bb = __float2bfloat16(a[0] - ff); l0.x = *(unsigned short*)&bb;
        bb = __float2bfloat16(a[1]); ff = __bfloat162float(bb); h0.y = *(unsigned short*)&bb;
        bb = __float2bfloat16(a[1] - ff); l0.y = *(unsigned short*)&bb;
        bb = __float2bfloat16(a[2]); ff = __bfloat162float(bb); h0.z = *(unsigned short*)&bb;
        bb = __float2bfloat16(a[2] - ff); l0.z = *(unsigned short*)&bb;
        bb = __float2bfloat16(a[3]); ff = __bfloat162float(bb); h0.w = *(unsigned short*)&bb;
        bb = __float2bfloat16(a[3] - ff); l0.w = *(unsigned short*)&bb;
        bb = __float2bfloat16(a[4]); ff = __bfloat162float(bb); h1.x = *(unsigned short*)&bb;
        bb = __float2bfloat16(a[4] - ff); l1.x = *(unsigned short*)&bb;
        bb = __float2bfloat16(a[5]); ff = __bfloat162float(bb); h1.y = *(unsigned short*)&bb;
        bb = __float2bfloat16(a[5] - ff); l1.y = *(unsigned short*)&bb;
        bb = __float2bfloat16(a[6]); ff = __bfloat162float(bb); h1.z = *(unsigned short*)&bb;
        bb = __float2bfloat16(a[6] - ff); l1.z = *(unsigned short*)&bb;
        bb = __float2bfloat16(a[7]); ff = __bfloat162float(bb); h1.w = *(unsigned short*)&bb;
        bb = __float2bfloat16(a[7] - ff); l1.w = *(unsigned short*)&bb;
        size_t base = (size_t)wid * 128 + h * 8;
        *(ushort4*)(outHi + base)     = h0;
        *(ushort4*)(outHi + base + 4) = h1;
        *(ushort4*)(outLo + base)     = l0;
        *(ushort4*)(outLo + base + 4) = l1;
    }
}

// ---------------------------------------------------------------------------
// Fused layer-3 agg (relu, no LN) + collapsed head: out = h @ Weff + beff.
// Wl transposed [(j*3+c)*16+h]: conflict-free (lanes h consecutive).
// ---------------------------------------------------------------------------
__global__ __launch_bounds__(128) void agg_head(
        const unsigned int* __restrict__ hb,
        const int* __restrict__ rowPtr,
        const int* __restrict__ srcList,
        const float* __restrict__ dinv,
        const float* __restrict__ b,
        const float* __restrict__ Weff,
        const float* __restrict__ beff,
        float* __restrict__ out, int n) {
    __shared__ float Wl[384];
    int tt = threadIdx.x;
    for (int idx = tt; idx < 384; idx += 128) {
        int f = idx / 3, c = idx - f * 3;
        int j = f & 7, hh = f >> 3;
        Wl[(j * 3 + c) * 16 + hh] = Weff[idx];
    }
    __syncthreads();

    int wid = (blockIdx.x * 128 + tt) >> 6;
    int lane = tt & 63;
    if (wid >= n) return;
    int h = lane & 15;
    int gg = lane >> 4;
    int e0 = rowPtr[wid], e1 = rowPtr[wid + 1];
    float dc = dinv[wid];
    const uint4* hb4 = (const uint4*)hb;
    uint4 us = hb4[(size_t)wid * 16 + h];

    float a[8];
#pragma unroll
    for (int j = 0; j < 8; j++) a[j] = 0.f;

    int idx0 = (e0 + gg < e1) ? srcList[e0 + gg] : -1;
    int idx1 = (e0 + 4 + gg < e1) ? srcList[e0 + 4 + gg] : -1;
    int e = e0;
    for (; e + 8 <= e1; e += 8) {
        int ni0 = (e + 8 + gg < e1) ? srcList[e + 8 + gg] : -1;
        int ni1 = (e + 12 + gg < e1) ? srcList[e + 12 + gg] : -1;
        uint4 u0 = hb4[(size_t)idx0 * 16 + h];
        uint4 u1 = hb4[(size_t)idx1 * 16 + h];
        a[0] += BF_LO(u0.x); a[1] += BF_HI(u0.x);
        a[2] += BF_LO(u0.y); a[3] += BF_HI(u0.y);
        a[4] += BF_LO(u0.z); a[5] += BF_HI(u0.z);
        a[6] += BF_LO(u0.w); a[7] += BF_HI(u0.w);
        a[0] += BF_LO(u1.x); a[1] += BF_HI(u1.x);
        a[2] += BF_LO(u1.y); a[3] += BF_HI(u1.y);
        a[4] += BF_LO(u1.z); a[5] += BF_HI(u1.z);
        a[6] += BF_LO(u1.w); a[7] += BF_HI(u1.w);
        idx0 = ni0; idx1 = ni1;
    }
    if (idx0 >= 0) {
        uint4 u = hb4[(size_t)idx0 * 16 + h];
        a[0] += BF_LO(u.x); a[1] += BF_HI(u.x);
        a[2] += BF_LO(u.y); a[3] += BF_HI(u.y);
        a[4] += BF_LO(u.z); a[5] += BF_HI(u.z);
        a[6] += BF_LO(u.w); a[7] += BF_HI(u.w);
    }
    if (idx1 >= 0) {
        uint4 u = hb4[(size_t)idx1 * 16 + h];
        a[0] += BF_LO(u.x); a[1] += BF_HI(u.x);
        a[2] += BF_LO(u.y); a[3] += BF_HI(u.y);
        a[4] += BF_LO(u.z); a[5] += BF_HI(u.z);
        a[6] += BF_LO(u.w); a[7] += BF_HI(u.w);
    }
#pragma unroll
    for (int j = 0; j < 8; j++) {
        a[j] += __shfl_xor(a[j], 16, 64);
        a[j] += __shfl_xor(a[j], 32, 64);
    }
    a[0] += BF_LO(us.x); a[1] += BF_HI(us.x);
    a[2] += BF_LO(us.y); a[3] += BF_HI(us.y);
    a[4] += BF_LO(us.z); a[5] += BF_HI(us.z);
    a[6] += BF_LO(us.w); a[7] += BF_HI(us.w);

    float4 bv0 = *(const float4*)(b + h * 8);
    float4 bv1 = *(const float4*)(b + h * 8 + 4);
    a[0] = fmaxf(a[0] * dc + bv0.x, 0.f);
    a[1] = fmaxf(a[1] * dc + bv0.y, 0.f);
    a[2] = fmaxf(a[2] * dc + bv0.z, 0.f);
    a[3] = fmaxf(a[3] * dc + bv0.w, 0.f);
    a[4] = fmaxf(a[4] * dc + bv1.x, 0.f);
    a[5] = fmaxf(a[5] * dc + bv1.y, 0.f);
    a[6] = fmaxf(a[6] * dc + bv1.z, 0.f);
    a[7] = fmaxf(a[7] * dc + bv1.w, 0.f);

    float p0 = 0.f, p1 = 0.f, p2 = 0.f;
#pragma unroll
    for (int j = 0; j < 8; j++) {
        p0 += a[j] * Wl[(j * 3 + 0) * 16 + h];
        p1 += a[j] * Wl[(j * 3 + 1) * 16 + h];
        p2 += a[j] * Wl[(j * 3 + 2) * 16 + h];
    }
#pragma unroll
    for (int m = 8; m >= 1; m >>= 1) {
        p0 += __shfl_xor(p0, m, 64);
        p1 += __shfl_xor(p1, m, 64);
        p2 += __shfl_xor(p2, m, 64);
    }
    if (lane == 0) {
        out[(size_t)wid * 3 + 0] = p0 + beff[0];
        out[(size_t)wid * 3 + 1] = p1 + beff[1];
        out[(size_t)wid * 3 + 2] = p2 + beff[2];
    }
}

// ---------------------------------------------------------------------------
// Head collapse: Weff = Wp1 @ Wp2 (128x3), beff = bp1 @ Wp2 + bp2.
// ---------------------------------------------------------------------------
__global__ __launch_bounds__(128) void head_collapse(const float* __restrict__ Wp1,
                                                     const float* __restrict__ bp1,
                                                     const float* __restrict__ Wp2,
                                                     const float* __restrict__ bp2,
                                                     float* __restrict__ Weff,
                                                     float* __restrict__ beff) {
    __shared__ float w2[384];
    int t = threadIdx.x;
    w2[t] = Wp2[t]; w2[t + 128] = Wp2[t + 128]; w2[t + 256] = Wp2[t + 256];
    __syncthreads();
    float p0 = 0.f, p1 = 0.f, p2 = 0.f;
    const float* wr = Wp1 + (size_t)t * 128;
    for (int k = 0; k < 128; k++) {
        float v = wr[k];
        p0 += v * w2[k * 3 + 0];
        p1 += v * w2[k * 3 + 1];
        p2 += v * w2[k * 3 + 2];
    }
    Weff[t * 3 + 0] = p0; Weff[t * 3 + 1] = p1; Weff[t * 3 + 2] = p2;
    if (t == 0) {
        float q0 = bp2[0], q1 = bp2[1], q2 = bp2[2];
        for (int k = 0; k < 128; k++) {
            float v = bp1[k];
            q0 += v * w2[k * 3 + 0];
            q1 += v * w2[k * 3 + 1];
            q2 += v * w2[k * 3 + 2];
        }
        beff[0] = q0; beff[1] = q1; beff[2] = q2;
    }
}

// ---------------------------------------------------------------------------
extern "C" void kernel_launch(void* const* d_in, const int* in_sizes, int n_in,
                              void* d_out, int out_size, void* d_ws, size_t ws_size,
                              hipStream_t stream) {
    const float* x   = (const float*)d_in[0];
    const int* ei    = (const int*)d_in[1];
    const float* W1  = (const float*)d_in[2];
    const float* b1  = (const float*)d_in[3];
    const float* W2  = (const float*)d_in[4];
    const float* b2  = (const float*)d_in[5];
    const float* W3  = (const float*)d_in[6];
    const float* b3  = (const float*)d_in[7];
    const float* g1  = (const float*)d_in[8];
    const float* be1 = (const float*)d_in[9];
    const float* g2  = (const float*)d_in[10];
    const float* be2 = (const float*)d_in[11];
    const float* Wp1f = (const float*)d_in[12];
    const float* bp1 = (const float*)d_in[13];
    const float* Wp2f = (const float*)d_in[14];
    const float* bp2 = (const float*)d_in[15];
    float* out = (float*)d_out;

    const int n = in_sizes[0] / 128;   // 50000
    const int E = in_sizes[1] / 2;     // 1600000
    const int* row = ei;
    const int* col = ei + E;

    char* ws = (char*)d_ws;
    size_t nA  = ((size_t)n * 4 + 255) & ~(size_t)255;
    size_t nA1 = ((size_t)(n + 1) * 4 + 255) & ~(size_t)255;
    size_t eA  = ((size_t)E * 4 + 255) & ~(size_t)255;
    size_t hbSz = ((size_t)n * 128 * 2 + 255) & ~(size_t)255;
    int*   rowPtr  = (int*)ws;
    float* dinvp   = (float*)(ws + nA1);
    int*   srcList = (int*)(ws + nA1 + nA);
    unsigned short* hbA = (unsigned short*)(ws + nA1 + nA + eA);
    unsigned short* hbB = hbA + hbSz / 2;
    unsigned short* Phi = hbB + hbSz / 2;
    unsigned short* Plo = Phi + hbSz / 2;
    unsigned short* Wq  = Plo + hbSz / 2;        // 3 x 32768 ushorts
    float* Weff = (float*)(Wq + 3 * 32768);
    float* beff = Weff + 384;
    // CSR scratch aliases Phi/Plo (consumed by bucket_fill before agg writes):
    unsigned long long* tmp = (unsigned long long*)Phi;
    int* chunkBH     = (int*)((char*)Phi + 2 * eA);
    int* bucketStart = (int*)((char*)Phi + 2 * eA + (size_t)NB * 256 * 4);

    const int nbuck = (n + 255) >> 8;                 // 196
    const int per   = (((E + NB - 1) / NB) + 15) & ~15;
    const int tileBlocks = (n + 63) / 64;             // 782
    const int nodeWaveBlocks = (n + 1) / 2;           // 25000

    // CSR build (bucketed counting sort, zero global atomics)
    bucket_hist<<<NB, 256, 0, stream>>>(col, chunkBH, E, per, nbuck);
    bucket_scan<<<1, 256, 0, stream>>>(chunkBH, bucketStart, rowPtr, E, n, nbuck, NB);
    scatter_pairs<<<NB, 256, 0, stream>>>(row, col, chunkBH, bucketStart, tmp, E, per, nbuck);
    bucket_fill<<<nbuck, 256, 0, stream>>>(tmp, bucketStart, rowPtr, dinvp, srcList, n);
    head_collapse<<<1, 128, 0, stream>>>(Wp1f, bp1, Wp2f, bp2, Weff, beff);
    pack_w_all<<<192, 256, 0, stream>>>(W1, W2, W3, Wq);

    // ---- layer 1 (x f32 -> in-register hi/lo split) ----
    gemm_mfma<0><<<tileBlocks, 256, 0, stream>>>(x, nullptr, nullptr, Wq, dinvp, hbA, n);
    agg_post<<<nodeWaveBlocks, 128, 0, stream>>>((const unsigned int*)hbA,
                                                 rowPtr, srcList, dinvp,
                                                 b1, g1, be1, Phi, Plo, n);
    // ---- layer 2 ----
    gemm_mfma<1><<<tileBlocks, 256, 0, stream>>>(nullptr, Phi, Plo, Wq + 32768, dinvp, hbB, n);
    agg_post<<<nodeWaveBlocks, 128, 0, stream>>>((const unsigned int*)hbB,
                                                 rowPtr, srcList, dinvp,
                                                 b2, g2, be2, Phi, Plo, n);
    // ---- layer 3 ----
    gemm_mfma<1><<<tileBlocks, 256, 0, stream>>>(nullptr, Phi, Plo, Wq + 65536, dinvp, hbA, n);
    agg_head<<<nodeWaveBlocks, 128, 0, stream>>>((const unsigned int*)hbA,
                                                 rowPtr, srcList, dinvp,
                                                 b3, Weff, beff, out, n);
}

// Round 12
// 361.273 us; speedup vs baseline: 1.2924x; 1.0083x over previous
//
#include <hip/hip_runtime.h>
#include <hip/hip_bf16.h>

#define EPS_LN 1e-5f
#define NB    256             // edge chunks for hist/scatter
#define SEGCAP 16384          // srcList segment capacity per bucket (64KB LDS)

typedef int ivec4 __attribute__((ext_vector_type(4)));
typedef short bf16x8v __attribute__((ext_vector_type(8)));
typedef float f32x4v __attribute__((ext_vector_type(4)));
typedef unsigned short u16x8 __attribute__((ext_vector_type(8)));

// ===========================================================================
// R32: more gather MLP on R31 (364us).
//  - agg_post/agg_head: 16-edge unrolled gather -> 4 uint4 gathers + 4 index
//    loads in flight per wave (was 2+2). Tail via guarded prefetched quad
//    (slot s = 4q+gg bijection covers <=15 leftovers exactly once).
//  - agg_head: head weights in registers (6x float4 from Weff, L2-resident);
//    LDS deleted -> SQ_LDS_BANK_CONFLICT 2.9M -> ~0.
//  - head_collapse merged into pack_w_all (block 192): one fewer launch.
// Everything else identical to R31.
// ===========================================================================

__global__ __launch_bounds__(256) void bucket_hist(const int* __restrict__ col,
                                                   int* __restrict__ chunkBH,
                                                   int E, int per, int nbuck) {
    __shared__ int hist[256];
    int t = threadIdx.x;
    hist[t] = 0;
    __syncthreads();
    int s0 = blockIdx.x * per;
    int s1 = s0 + per; if (s1 > E) s1 = E;
    if (s0 < s1) {
        int q0 = s0 >> 2, q1 = s1 >> 2;
        for (int i = q0 + t; i < q1; i += 256) {
            ivec4 c = __builtin_nontemporal_load((const ivec4*)col + i);
            atomicAdd(&hist[c.x >> 8], 1);
            atomicAdd(&hist[c.y >> 8], 1);
            atomicAdd(&hist[c.z >> 8], 1);
            atomicAdd(&hist[c.w >> 8], 1);
        }
        for (int i = (q1 << 2) + t; i < s1; i += 256)
            atomicAdd(&hist[col[i] >> 8], 1);
    }
    __syncthreads();
    if (t < nbuck) chunkBH[blockIdx.x * 256 + t] = hist[t];   // [k][b], coalesced
}

__global__ __launch_bounds__(256) void bucket_scan(int* __restrict__ chunkBH,
                                                   int* __restrict__ bucketStart,
                                                   int* __restrict__ rowPtr,
                                                   int E, int n, int nbuck, int nb) {
    __shared__ int tot[256];
    int t = threadIdx.x;
    int run = 0;
    if (t < nbuck) {
        for (int k0 = 0; k0 < nb; k0 += 16) {
            int v[16];
#pragma unroll
            for (int j = 0; j < 16; j++)
                v[j] = (k0 + j < nb) ? chunkBH[(k0 + j) * 256 + t] : 0;
#pragma unroll
            for (int j = 0; j < 16; j++) {
                int tv = v[j];
                if (k0 + j < nb) chunkBH[(k0 + j) * 256 + t] = run;
                run += tv;
            }
        }
    }
    tot[t] = run;
    __syncthreads();
    for (int d = 1; d < 256; d <<= 1) {
        int add = (t >= d) ? tot[t - d] : 0;
        __syncthreads();
        tot[t] += add;
        __syncthreads();
    }
    if (t < nbuck) bucketStart[t] = tot[t] - run;
    if (t == 0) { bucketStart[nbuck] = E; rowPtr[n] = E; }
}

__global__ __launch_bounds__(256) void scatter_pairs(const int* __restrict__ row,
                                                     const int* __restrict__ col,
                                                     const int* __restrict__ chunkBH,
                                                     const int* __restrict__ bucketStart,
                                                     unsigned long long* __restrict__ tmp,
                                                     int E, int per, int nbuck) {
    __shared__ int curs[256];
    int t = threadIdx.x;
    int k = blockIdx.x;
    curs[t] = (t < nbuck) ? (chunkBH[k * 256 + t] + bucketStart[t]) : 0;
    __syncthreads();
    int s0 = k * per;
    int s1 = s0 + per; if (s1 > E) s1 = E;
    if (s0 >= s1) return;
    int q0 = s0 >> 2, q1 = s1 >> 2;
    for (int i = q0 + t; i < q1; i += 256) {
        ivec4 c4 = __builtin_nontemporal_load((const ivec4*)col + i);
        ivec4 r4 = __builtin_nontemporal_load((const ivec4*)row + i);
        int p0 = atomicAdd(&curs[c4.x >> 8], 1);
        tmp[p0] = ((unsigned long long)(unsigned)c4.x << 32) | (unsigned)r4.x;
        int p1 = atomicAdd(&curs[c4.y >> 8], 1);
        tmp[p1] = ((unsigned long long)(unsigned)c4.y << 32) | (unsigned)r4.y;
        int p2 = atomicAdd(&curs[c4.z >> 8], 1);
        tmp[p2] = ((unsigned long long)(unsigned)c4.z << 32) | (unsigned)r4.z;
        int p3 = atomicAdd(&curs[c4.w >> 8], 1);
        tmp[p3] = ((unsigned long long)(unsigned)c4.w << 32) | (unsigned)r4.w;
    }
    for (int i = (q1 << 2) + t; i < s1; i += 256) {
        int c = col[i], r = row[i];
        int p = atomicAdd(&curs[c >> 8], 1);
        tmp[p] = ((unsigned long long)(unsigned)c << 32) | (unsigned)r;
    }
}

__global__ __launch_bounds__(256) void bucket_fill(const unsigned long long* __restrict__ tmp,
                                                   const int* __restrict__ bucketStart,
                                                   int* __restrict__ rowPtr,
                                                   float* __restrict__ dinv,
                                                   int* __restrict__ srcList,
                                                   int n) {
    __shared__ int cnt[256];
    __shared__ int cur[256];
    __shared__ int seg[SEGCAP];
    int b = blockIdx.x, t = threadIdx.x;
    int node0 = b << 8;
    int s0 = bucketStart[b], s1 = bucketStart[b + 1];
    int len = s1 - s0;
    cnt[t] = 0;
    __syncthreads();
    for (int i = s0 + t; i < s1; i += 256) {
        int c = (int)(tmp[i] >> 32);
        atomicAdd(&cnt[c - node0], 1);
    }
    __syncthreads();
    int v = cnt[t];
    cur[t] = v;
    __syncthreads();
    for (int d = 1; d < 256; d <<= 1) {
        int add = (t >= d) ? cur[t - d] : 0;
        __syncthreads();
        cur[t] += add;
        __syncthreads();
    }
    int excl = cur[t] - v;
    int node = node0 + t;
    if (node < n) {
        rowPtr[node] = s0 + excl;
        dinv[node] = rsqrtf((float)v + 1.0f);   // +1 self-loop
    }
    cur[t] = excl;
    __syncthreads();
    if (len <= SEGCAP) {
        for (int i = s0 + t; i < s1; i += 256) {
            unsigned long long p = tmp[i];
            int c = (int)(p >> 32);
            int r = (int)(p & 0xffffffffu);
            int pos = atomicAdd(&cur[c - node0], 1);
            seg[pos] = r;
        }
        __syncthreads();
        for (int i = t; i < len; i += 256)
            srcList[s0 + i] = seg[i];
    } else {                                    // overflow fallback (never for this graph)
        for (int i = s0 + t; i < s1; i += 256) {
            unsigned long long p = tmp[i];
            int c = (int)(p >> 32);
            int r = (int)(p & 0xffffffffu);
            int pos = atomicAdd(&cur[c - node0], 1);
            srcList[s0 + pos] = r;
        }
    }
}

// ---------------------------------------------------------------------------
// pack_w_all + head_collapse fused. Blocks 0..191: pack W1/W2/W3 into MFMA
// B-fragment bf16 hi/lo planes. Block 192: Weff = Wp1@Wp2, beff = bp1@Wp2+bp2.
// ---------------------------------------------------------------------------
__global__ __launch_bounds__(256) void pack_w_all(const float* __restrict__ W1,
                                                  const float* __restrict__ W2,
                                                  const float* __restrict__ W3,
                                                  unsigned short* __restrict__ Wq,
                                                  const float* __restrict__ Wp1,
                                                  const float* __restrict__ bp1,
                                                  const float* __restrict__ Wp2,
                                                  const float* __restrict__ bp2,
                                                  float* __restrict__ Weff,
                                                  float* __restrict__ beff) {
    if (blockIdx.x == 192) {                     // head collapse
        __shared__ float w2[384];
        int t = threadIdx.x;
        for (int idx = t; idx < 384; idx += 256) w2[idx] = Wp2[idx];
        __syncthreads();
        if (t < 128) {
            float p0 = 0.f, p1 = 0.f, p2 = 0.f;
            const float* wr = Wp1 + (size_t)t * 128;
            for (int k = 0; k < 128; k++) {
                float v = wr[k];
                p0 += v * w2[k * 3 + 0];
                p1 += v * w2[k * 3 + 1];
                p2 += v * w2[k * 3 + 2];
            }
            Weff[t * 3 + 0] = p0; Weff[t * 3 + 1] = p1; Weff[t * 3 + 2] = p2;
            if (t == 0) {
                float q0 = bp2[0], q1 = bp2[1], q2 = bp2[2];
                for (int k = 0; k < 128; k++) {
                    float v = bp1[k];
                    q0 += v * w2[k * 3 + 0];
                    q1 += v * w2[k * 3 + 1];
                    q2 += v * w2[k * 3 + 2];
                }
                beff[0] = q0; beff[1] = q1; beff[2] = q2;
            }
        }
        return;
    }
    int w = blockIdx.x >> 6;
    const float* W = (w == 0) ? W1 : (w == 1) ? W2 : W3;
    unsigned short* Wp = Wq + (size_t)w * 32768;
    int s = (blockIdx.x & 63) * 256 + threadIdx.x;   // 0..16383
    int i = s & 7;
    int lane = (s >> 3) & 63;
    int jt = (s >> 9) & 7;
    int kb = s >> 12;
    int k = kb * 32 + ((lane >> 4) & 3) * 8 + i;
    int nn = jt * 16 + (lane & 15);
    float v = W[k * 128 + nn];
    __hip_bfloat16 hi = __float2bfloat16(v);
    float hf = __bfloat162float(hi);
    __hip_bfloat16 lo = __float2bfloat16(v - hf);
    Wp[s]         = *(unsigned short*)&hi;
    Wp[16384 + s] = *(unsigned short*)&lo;
}

// ---------------------------------------------------------------------------
// MFMA gemm core. B staged in LDS per kb-slice (16KB), loaded once per block.
// 3 MFMA per (kb,jt): ah*bh + ah*bl + al*bh (~f32 precision).
// ---------------------------------------------------------------------------
__device__ __forceinline__ void split8(const float* __restrict__ p,
                                       bf16x8v& ah, bf16x8v& al) {
#pragma unroll
    for (int i = 0; i < 8; i++) {
        float v = p[i];
        __hip_bfloat16 hb = __float2bfloat16(v);
        float hf = __bfloat162float(hb);
        __hip_bfloat16 lb = __float2bfloat16(v - hf);
        ah[i] = *(short*)&hb;
        al[i] = *(short*)&lb;
    }
}

template<int ASRC>   // 0: f32 A (split in-register), 1: hi/lo bf16 planes
__global__ __launch_bounds__(256) void gemm_mfma(const float* __restrict__ Af32,
                                                 const unsigned short* __restrict__ Ahi,
                                                 const unsigned short* __restrict__ Alo,
                                                 const unsigned short* __restrict__ Wp,
                                                 const float* __restrict__ dinv,
                                                 unsigned short* __restrict__ hbOut,
                                                 int n) {
    __shared__ unsigned short Bs[8192];   // hi[4096] || lo[4096] for one kb-slice

    const int tx = threadIdx.x;
    const int wv = tx >> 6;
    const int l  = tx & 63;
    const int m0 = blockIdx.x * 64 + wv * 16;
    int arow = m0 + (l & 15);
    if (arow >= n) arow = 0;            // clamped rows only affect unstored outputs
    const int kofs = (l >> 4) * 8;

    f32x4v acc[8];
#pragma unroll
    for (int jt = 0; jt < 8; jt++) acc[jt] = (f32x4v){0.f, 0.f, 0.f, 0.f};

#pragma unroll
    for (int kb = 0; kb < 4; kb++) {
        __syncthreads();   // protect previous slice's reads
        {   // stage 4096 hi + 4096 lo ushorts: 16+16 per thread
            u16x8* dH = (u16x8*)&Bs[tx * 16];
            const u16x8* sH = (const u16x8*)(Wp + kb * 4096 + tx * 16);
            dH[0] = sH[0]; dH[1] = sH[1];
            u16x8* dL = (u16x8*)&Bs[4096 + tx * 16];
            const u16x8* sL = (const u16x8*)(Wp + 16384 + kb * 4096 + tx * 16);
            dL[0] = sL[0]; dL[1] = sL[1];
        }
        bf16x8v ah, al;
        if (ASRC == 0) {
            split8(Af32 + (size_t)arow * 128 + kb * 32 + kofs, ah, al);
        } else {
            ah = *(const bf16x8v*)(Ahi + (size_t)arow * 128 + kb * 32 + kofs);
            al = *(const bf16x8v*)(Alo + (size_t)arow * 128 + kb * 32 + kofs);
        }
        __syncthreads();
#pragma unroll
        for (int jt = 0; jt < 8; jt++) {
            bf16x8v bh = *(const bf16x8v*)&Bs[jt * 512 + l * 8];
            bf16x8v bl = *(const bf16x8v*)&Bs[4096 + jt * 512 + l * 8];
            acc[jt] = __builtin_amdgcn_mfma_f32_16x16x32_bf16(ah, bh, acc[jt], 0, 0, 0);
            acc[jt] = __builtin_amdgcn_mfma_f32_16x16x32_bf16(ah, bl, acc[jt], 0, 0, 0);
            acc[jt] = __builtin_amdgcn_mfma_f32_16x16x32_bf16(al, bh, acc[jt], 0, 0, 0);
        }
    }

    const int r0 = m0 + (l >> 4) * 4;
    const int colb = l & 15;
#pragma unroll
    for (int r = 0; r < 4; r++) {
        int grow = r0 + r;
        if (grow < n) {
            float dv = dinv[grow];
#pragma unroll
            for (int jt = 0; jt < 8; jt++) {
                __hip_bfloat16 t = __float2bfloat16(acc[jt][r] * dv);
                hbOut[(size_t)grow * 128 + jt * 16 + colb] = *(unsigned short*)&t;
            }
        }
    }
}

#define BF_LO(u) __uint_as_float((u) << 16)
#define BF_HI(u) __uint_as_float((u) & 0xffff0000u)

#define ACC8(u)  do { \
    a[0] += BF_LO((u).x); a[1] += BF_HI((u).x); \
    a[2] += BF_LO((u).y); a[3] += BF_HI((u).y); \
    a[4] += BF_LO((u).z); a[5] += BF_HI((u).z); \
    a[6] += BF_LO((u).w); a[7] += BF_HI((u).w); } while (0)

// ---------------------------------------------------------------------------
// agg_post (LN layers): 16-edge unrolled gather (4 uint4 + 4 idx in flight);
// output = hi/lo bf16 planes.
// ---------------------------------------------------------------------------
__global__ __launch_bounds__(128) void agg_post(const unsigned int* __restrict__ hb,
                                                const int* __restrict__ rowPtr,
                                                const int* __restrict__ srcList,
                                                const float* __restrict__ dinv,
                                                const float* __restrict__ b,
                                                const float* __restrict__ g,
                                                const float* __restrict__ beta,
                                                unsigned short* __restrict__ outHi,
                                                unsigned short* __restrict__ outLo,
                                                int n) {
    int wid = (blockIdx.x * 128 + threadIdx.x) >> 6;
    int lane = threadIdx.x & 63;
    if (wid >= n) return;
    int h = lane & 15;
    int gg = lane >> 4;
    int e0 = rowPtr[wid], e1 = rowPtr[wid + 1];
    float dc = dinv[wid];
    const uint4* hb4 = (const uint4*)hb;

    uint4 us = hb4[(size_t)wid * 16 + h];

    float a[8];
#pragma unroll
    for (int j = 0; j < 8; j++) a[j] = 0.f;

    int idx0 = (e0 + 0 + gg < e1) ? srcList[e0 + 0 + gg] : -1;
    int idx1 = (e0 + 4 + gg < e1) ? srcList[e0 + 4 + gg] : -1;
    int idx2 = (e0 + 8 + gg < e1) ? srcList[e0 + 8 + gg] : -1;
    int idx3 = (e0 + 12 + gg < e1) ? srcList[e0 + 12 + gg] : -1;
    int e = e0;
    for (; e + 16 <= e1; e += 16) {
        int ni0 = (e + 16 + gg < e1) ? srcList[e + 16 + gg] : -1;
        int ni1 = (e + 20 + gg < e1) ? srcList[e + 20 + gg] : -1;
        int ni2 = (e + 24 + gg < e1) ? srcList[e + 24 + gg] : -1;
        int ni3 = (e + 28 + gg < e1) ? srcList[e + 28 + gg] : -1;
        uint4 u0 = hb4[(size_t)idx0 * 16 + h];
        uint4 u1 = hb4[(size_t)idx1 * 16 + h];
        uint4 u2 = hb4[(size_t)idx2 * 16 + h];
        uint4 u3 = hb4[(size_t)idx3 * 16 + h];
        ACC8(u0); ACC8(u1); ACC8(u2); ACC8(u3);
        idx0 = ni0; idx1 = ni1; idx2 = ni2; idx3 = ni3;
    }
    // tail (<16 edges): slots e+4q+gg, each guarded at prefetch
    if (idx0 >= 0) { uint4 u = hb4[(size_t)idx0 * 16 + h]; ACC8(u); }
    if (idx1 >= 0) { uint4 u = hb4[(size_t)idx1 * 16 + h]; ACC8(u); }
    if (idx2 >= 0) { uint4 u = hb4[(size_t)idx2 * 16 + h]; ACC8(u); }
    if (idx3 >= 0) { uint4 u = hb4[(size_t)idx3 * 16 + h]; ACC8(u); }

#pragma unroll
    for (int j = 0; j < 8; j++) {
        a[j] += __shfl_xor(a[j], 16, 64);
        a[j] += __shfl_xor(a[j], 32, 64);
    }
    ACC8(us);   // self-loop, same dc scaling as gather terms

    float4 bv0 = *(const float4*)(b + h * 8);
    float4 bv1 = *(const float4*)(b + h * 8 + 4);
    a[0] = fmaxf(a[0] * dc + bv0.x, 0.f);
    a[1] = fmaxf(a[1] * dc + bv0.y, 0.f);
    a[2] = fmaxf(a[2] * dc + bv0.z, 0.f);
    a[3] = fmaxf(a[3] * dc + bv0.w, 0.f);
    a[4] = fmaxf(a[4] * dc + bv1.x, 0.f);
    a[5] = fmaxf(a[5] * dc + bv1.y, 0.f);
    a[6] = fmaxf(a[6] * dc + bv1.z, 0.f);
    a[7] = fmaxf(a[7] * dc + bv1.w, 0.f);

    float s = ((a[0] + a[1]) + (a[2] + a[3])) + ((a[4] + a[5]) + (a[6] + a[7]));
#pragma unroll
    for (int m = 8; m >= 1; m >>= 1) s += __shfl_xor(s, m, 64);
    float mu = s * (1.f / 128.f);
    float sq = 0.f;
    float d[8];
#pragma unroll
    for (int j = 0; j < 8; j++) { d[j] = a[j] - mu; sq += d[j] * d[j]; }
#pragma unroll
    for (int m = 8; m >= 1; m >>= 1) sq += __shfl_xor(sq, m, 64);
    float rs = rsqrtf(sq * (1.f / 128.f) + EPS_LN);
    float4 gv0 = *(const float4*)(g + h * 8);
    float4 gv1 = *(const float4*)(g + h * 8 + 4);
    float4 bt0 = *(const float4*)(beta + h * 8);
    float4 bt1 = *(const float4*)(beta + h * 8 + 4);
    a[0] = d[0] * rs * gv0.x + bt0.x;
    a[1] = d[1] * rs * gv0.y + bt0.y;
    a[2] = d[2] * rs * gv0.z + bt0.z;
    a[3] = d[3] * rs * gv0.w + bt0.w;
    a[4] = d[4] * rs * gv1.x + bt1.x;
    a[5] = d[5] * rs * gv1.y + bt1.y;
    a[6] = d[6] * rs * gv1.z + bt1.z;
    a[7] = d[7] * rs * gv1.w + bt1.w;

    if (gg == 0) {
        ushort4 h0, h1, l0, l1;
        __hip_bfloat16 bb; float ff;
        bb = __float2bfloat16(a[0]); ff = __bfloat162float(bb); h0.x = *(unsigned short*)&bb;
        bb = __float2bfloat16(a[0] - ff); l0.x = *(unsigned short*)&bb;
        bb = __float2bfloat16(a[1]); ff = __bfloat162float(bb); h0.y = *(unsigned short*)&bb;
        bb = __float2bfloat16(a[1] - ff); l0.y = *(unsigned short*)&bb;
        bb = __float2bfloat16(a[2]); ff = __bfloat162float(bb); h0.z = *(unsigned short*)&bb;
        bb = __float2bfloat16(a[2] - ff); l0.z = *(unsigned short*)&bb;
        bb = __float2bfloat16(a[3]); ff = __bfloat162float(bb); h0.w = *(unsigned short*)&bb;
        bb = __float2bfloat16(a[3] - ff); l0.w = *(unsigned short*)&bb;
        bb = __float2bfloat16(a[4]); ff = __bfloat162float(bb); h1.x = *(unsigned short*)&bb;
        bb = __float2bfloat16(a[4] - ff); l1.x = *(unsigned short*)&bb;
        bb = __float2bfloat16(a[5]); ff = __bfloat162float(bb); h1.y = *(unsigned short*)&bb;
        bb = __float2bfloat16(a[5] - ff); l1.y = *(unsigned short*)&bb;
        bb = __float2bfloat16(a[6]); ff = __bfloat162float(bb); h1.z = *(unsigned short*)&bb;
        bb = __float2bfloat16(a[6] - ff); l1.z = *(unsigned short*)&bb;
        bb = __float2bfloat16(a[7]); ff = __bfloat162float(bb); h1.w = *(unsigned short*)&bb;
        bb = __float2bfloat16(a[7] - ff); l1.w = *(unsigned short*)&bb;
        size_t base = (size_t)wid * 128 + h * 8;
        *(ushort4*)(outHi + base)     = h0;
        *(ushort4*)(outHi + base + 4) = h1;
        *(ushort4*)(outLo + base)     = l0;
        *(ushort4*)(outLo + base + 4) = l1;
    }
}

// ---------------------------------------------------------------------------
// Fused layer-3 agg (relu, no LN) + collapsed head. Head weights in registers
// (6x float4 from Weff, lane h's 24 consecutive floats). No LDS.
// ---------------------------------------------------------------------------
__global__ __launch_bounds__(128) void agg_head(
        const unsigned int* __restrict__ hb,
        const int* __restrict__ rowPtr,
        const int* __restrict__ srcList,
        const float* __restrict__ dinv,
        const float* __restrict__ b,
        const float* __restrict__ Weff,
        const float* __restrict__ beff,
        float* __restrict__ out, int n) {
    int tt = threadIdx.x;
    int wid = (blockIdx.x * 128 + tt) >> 6;
    int lane = tt & 63;
    if (wid >= n) return;
    int h = lane & 15;
    int gg = lane >> 4;
    int e0 = rowPtr[wid], e1 = rowPtr[wid + 1];
    float dc = dinv[wid];
    const uint4* hb4 = (const uint4*)hb;
    uint4 us = hb4[(size_t)wid * 16 + h];

    // head weights for features 8h..8h+7: Weff[24h .. 24h+23]
    float wreg[24];
    {
        const float4* wp = (const float4*)(Weff + 24 * h);
#pragma unroll
        for (int q = 0; q < 6; q++) {
            float4 v = wp[q];
            wreg[4 * q + 0] = v.x; wreg[4 * q + 1] = v.y;
            wreg[4 * q + 2] = v.z; wreg[4 * q + 3] = v.w;
        }
    }

    float a[8];
#pragma unroll
    for (int j = 0; j < 8; j++) a[j] = 0.f;

    int idx0 = (e0 + 0 + gg < e1) ? srcList[e0 + 0 + gg] : -1;
    int idx1 = (e0 + 4 + gg < e1) ? srcList[e0 + 4 + gg] : -1;
    int idx2 = (e0 + 8 + gg < e1) ? srcList[e0 + 8 + gg] : -1;
    int idx3 = (e0 + 12 + gg < e1) ? srcList[e0 + 12 + gg] : -1;
    int e = e0;
    for (; e + 16 <= e1; e += 16) {
        int ni0 = (e + 16 + gg < e1) ? srcList[e + 16 + gg] : -1;
        int ni1 = (e + 20 + gg < e1) ? srcList[e + 20 + gg] : -1;
        int ni2 = (e + 24 + gg < e1) ? srcList[e + 24 + gg] : -1;
        int ni3 = (e + 28 + gg < e1) ? srcList[e + 28 + gg] : -1;
        uint4 u0 = hb4[(size_t)idx0 * 16 + h];
        uint4 u1 = hb4[(size_t)idx1 * 16 + h];
        uint4 u2 = hb4[(size_t)idx2 * 16 + h];
        uint4 u3 = hb4[(size_t)idx3 * 16 + h];
        ACC8(u0); ACC8(u1); ACC8(u2); ACC8(u3);
        idx0 = ni0; idx1 = ni1; idx2 = ni2; idx3 = ni3;
    }
    if (idx0 >= 0) { uint4 u = hb4[(size_t)idx0 * 16 + h]; ACC8(u); }
    if (idx1 >= 0) { uint4 u = hb4[(size_t)idx1 * 16 + h]; ACC8(u); }
    if (idx2 >= 0) { uint4 u = hb4[(size_t)idx2 * 16 + h]; ACC8(u); }
    if (idx3 >= 0) { uint4 u = hb4[(size_t)idx3 * 16 + h]; ACC8(u); }

#pragma unroll
    for (int j = 0; j < 8; j++) {
        a[j] += __shfl_xor(a[j], 16, 64);
        a[j] += __shfl_xor(a[j], 32, 64);
    }
    ACC8(us);

    float4 bv0 = *(const float4*)(b + h * 8);
    float4 bv1 = *(const float4*)(b + h * 8 + 4);
    a[0] = fmaxf(a[0] * dc + bv0.x, 0.f);
    a[1] = fmaxf(a[1] * dc + bv0.y, 0.f);
    a[2] = fmaxf(a[2] * dc + bv0.z, 0.f);
    a[3] = fmaxf(a[3] * dc + bv0.w, 0.f);
    a[4] = fmaxf(a[4] * dc + bv1.x, 0.f);
    a[5] = fmaxf(a[5] * dc + bv1.y, 0.f);
    a[6] = fmaxf(a[6] * dc + bv1.z, 0.f);
    a[7] = fmaxf(a[7] * dc + bv1.w, 0.f);

    float p0 = 0.f, p1 = 0.f, p2 = 0.f;
#pragma unroll
    for (int j = 0; j < 8; j++) {
        p0 += a[j] * wreg[j * 3 + 0];
        p1 += a[j] * wreg[j * 3 + 1];
        p2 += a[j] * wreg[j * 3 + 2];
    }
#pragma unroll
    for (int m = 8; m >= 1; m >>= 1) {
        p0 += __shfl_xor(p0, m, 64);
        p1 += __shfl_xor(p1, m, 64);
        p2 += __shfl_xor(p2, m, 64);
    }
    if (lane == 0) {
        out[(size_t)wid * 3 + 0] = p0 + beff[0];
        out[(size_t)wid * 3 + 1] = p1 + beff[1];
        out[(size_t)wid * 3 + 2] = p2 + beff[2];
    }
}

// ---------------------------------------------------------------------------
extern "C" void kernel_launch(void* const* d_in, const int* in_sizes, int n_in,
                              void* d_out, int out_size, void* d_ws, size_t ws_size,
                              hipStream_t stream) {
    const float* x   = (const float*)d_in[0];
    const int* ei    = (const int*)d_in[1];
    const float* W1  = (const float*)d_in[2];
    const float* b1  = (const float*)d_in[3];
    const float* W2  = (const float*)d_in[4];
    const float* b2  = (const float*)d_in[5];
    const float* W3  = (const float*)d_in[6];
    const float* b3  = (const float*)d_in[7];
    const float* g1  = (const float*)d_in[8];
    const float* be1 = (const float*)d_in[9];
    const float* g2  = (const float*)d_in[10];
    const float* be2 = (const float*)d_in[11];
    const float* Wp1f = (const float*)d_in[12];
    const float* bp1 = (const float*)d_in[13];
    const float* Wp2f = (const float*)d_in[14];
    const float* bp2 = (const float*)d_in[15];
    float* out = (float*)d_out;

    const int n = in_sizes[0] / 128;   // 50000
    const int E = in_sizes[1] / 2;     // 1600000
    const int* row = ei;
    const int* col = ei + E;

    char* ws = (char*)d_ws;
    size_t nA  = ((size_t)n * 4 + 255) & ~(size_t)255;
    size_t nA1 = ((size_t)(n + 1) * 4 + 255) & ~(size_t)255;
    size_t eA  = ((size_t)E * 4 + 255) & ~(size_t)255;
    size_t hbSz = ((size_t)n * 128 * 2 + 255) & ~(size_t)255;
    int*   rowPtr  = (int*)ws;
    float* dinvp   = (float*)(ws + nA1);
    int*   srcList = (int*)(ws + nA1 + nA);
    unsigned short* hbA = (unsigned short*)(ws + nA1 + nA + eA);
    unsigned short* hbB = hbA + hbSz / 2;
    unsigned short* Phi = hbB + hbSz / 2;
    unsigned short* Plo = Phi + hbSz / 2;
    unsigned short* Wq  = Plo + hbSz / 2;        // 3 x 32768 ushorts
    float* Weff = (float*)(Wq + 3 * 32768);
    float* beff = Weff + 384;
    // CSR scratch aliases Phi/Plo (consumed by bucket_fill before agg writes):
    unsigned long long* tmp = (unsigned long long*)Phi;
    int* chunkBH     = (int*)((char*)Phi + 2 * eA);
    int* bucketStart = (int*)((char*)Phi + 2 * eA + (size_t)NB * 256 * 4);

    const int nbuck = (n + 255) >> 8;                 // 196
    const int per   = (((E + NB - 1) / NB) + 15) & ~15;
    const int tileBlocks = (n + 63) / 64;             // 782
    const int nodeWaveBlocks = (n + 1) / 2;           // 25000

    // CSR build (bucketed counting sort, zero global atomics)
    bucket_hist<<<NB, 256, 0, stream>>>(col, chunkBH, E, per, nbuck);
    bucket_scan<<<1, 256, 0, stream>>>(chunkBH, bucketStart, rowPtr, E, n, nbuck, NB);
    scatter_pairs<<<NB, 256, 0, stream>>>(row, col, chunkBH, bucketStart, tmp, E, per, nbuck);
    bucket_fill<<<nbuck, 256, 0, stream>>>(tmp, bucketStart, rowPtr, dinvp, srcList, n);
    pack_w_all<<<193, 256, 0, stream>>>(W1, W2, W3, Wq, Wp1f, bp1, Wp2f, bp2, Weff, beff);

    // ---- layer 1 (x f32 -> in-register hi/lo split) ----
    gemm_mfma<0><<<tileBlocks, 256, 0, stream>>>(x, nullptr, nullptr, Wq, dinvp, hbA, n);
    agg_post<<<nodeWaveBlocks, 128, 0, stream>>>((const unsigned int*)hbA,
                                                 rowPtr, srcList, dinvp,
                                                 b1, g1, be1, Phi, Plo, n);
    // ---- layer 2 ----
    gemm_mfma<1><<<tileBlocks, 256, 0, stream>>>(nullptr, Phi, Plo, Wq + 32768, dinvp, hbB, n);
    agg_post<<<nodeWaveBlocks, 128, 0, stream>>>((const unsigned int*)hbB,
                                                 rowPtr, srcList, dinvp,
                                                 b2, g2, be2, Phi, Plo, n);
    // ---- layer 3 ----
    gemm_mfma<1><<<tileBlocks, 256, 0, stream>>>(nullptr, Phi, Plo, Wq + 65536, dinvp, hbA, n);
    agg_head<<<nodeWaveBlocks, 128, 0, stream>>>((const unsigned int*)hbA,
                                                 rowPtr, srcList, dinvp,
                                                 b3, Weff, beff, out, n);
}

// Round 13
// 356.488 us; speedup vs baseline: 1.3097x; 1.0134x over previous
//
#include <hip/hip_runtime.h>
#include <hip/hip_bf16.h>

#define EPS_LN 1e-5f
#define NB    256             // edge chunks for hist/scatter
#define SEGCAP 16384          // srcList segment capacity per bucket (64KB LDS)

typedef int ivec4 __attribute__((ext_vector_type(4)));
typedef short bf16x8v __attribute__((ext_vector_type(8)));
typedef float f32x4v __attribute__((ext_vector_type(4)));
typedef unsigned short u16x8 __attribute__((ext_vector_type(8)));

// ===========================================================================
// R33: occupancy restore + gemm staging amortization on R32 (361us).
//  - agg_post/agg_head: back to the 8-edge unroll (R28's best: 24 VGPR, 69%
//    occ). R32's 16-deep unroll raised VGPR to 48 -> occ 45% and LOST time:
//    the gather is random-fetch-HBM-bound (151MB @ ~2.6TB/s random ceiling);
//    waves in flight matter more than per-wave ILP.
//  - agg_head: keep LDS-free reg weights (conflicts 0) but load wreg AFTER
//    the gather loop (gather regs dead -> peak VGPR ~28).
//  - gemm: 128-row tiles, 512 threads, 391 blocks: B kb-slice staged once
//    for 8 waves (was 4) -> half the staging + barriers per output row.
// Everything else identical to R32.
// ===========================================================================

__global__ __launch_bounds__(256) void bucket_hist(const int* __restrict__ col,
                                                   int* __restrict__ chunkBH,
                                                   int E, int per, int nbuck) {
    __shared__ int hist[256];
    int t = threadIdx.x;
    hist[t] = 0;
    __syncthreads();
    int s0 = blockIdx.x * per;
    int s1 = s0 + per; if (s1 > E) s1 = E;
    if (s0 < s1) {
        int q0 = s0 >> 2, q1 = s1 >> 2;
        for (int i = q0 + t; i < q1; i += 256) {
            ivec4 c = __builtin_nontemporal_load((const ivec4*)col + i);
            atomicAdd(&hist[c.x >> 8], 1);
            atomicAdd(&hist[c.y >> 8], 1);
            atomicAdd(&hist[c.z >> 8], 1);
            atomicAdd(&hist[c.w >> 8], 1);
        }
        for (int i = (q1 << 2) + t; i < s1; i += 256)
            atomicAdd(&hist[col[i] >> 8], 1);
    }
    __syncthreads();
    if (t < nbuck) chunkBH[blockIdx.x * 256 + t] = hist[t];   // [k][b], coalesced
}

__global__ __launch_bounds__(256) void bucket_scan(int* __restrict__ chunkBH,
                                                   int* __restrict__ bucketStart,
                                                   int* __restrict__ rowPtr,
                                                   int E, int n, int nbuck, int nb) {
    __shared__ int tot[256];
    int t = threadIdx.x;
    int run = 0;
    if (t < nbuck) {
        for (int k0 = 0; k0 < nb; k0 += 16) {
            int v[16];
#pragma unroll
            for (int j = 0; j < 16; j++)
                v[j] = (k0 + j < nb) ? chunkBH[(k0 + j) * 256 + t] : 0;
#pragma unroll
            for (int j = 0; j < 16; j++) {
                int tv = v[j];
                if (k0 + j < nb) chunkBH[(k0 + j) * 256 + t] = run;
                run += tv;
            }
        }
    }
    tot[t] = run;
    __syncthreads();
    for (int d = 1; d < 256; d <<= 1) {
        int add = (t >= d) ? tot[t - d] : 0;
        __syncthreads();
        tot[t] += add;
        __syncthreads();
    }
    if (t < nbuck) bucketStart[t] = tot[t] - run;
    if (t == 0) { bucketStart[nbuck] = E; rowPtr[n] = E; }
}

__global__ __launch_bounds__(256) void scatter_pairs(const int* __restrict__ row,
                                                     const int* __restrict__ col,
                                                     const int* __restrict__ chunkBH,
                                                     const int* __restrict__ bucketStart,
                                                     unsigned long long* __restrict__ tmp,
                                                     int E, int per, int nbuck) {
    __shared__ int curs[256];
    int t = threadIdx.x;
    int k = blockIdx.x;
    curs[t] = (t < nbuck) ? (chunkBH[k * 256 + t] + bucketStart[t]) : 0;
    __syncthreads();
    int s0 = k * per;
    int s1 = s0 + per; if (s1 > E) s1 = E;
    if (s0 >= s1) return;
    int q0 = s0 >> 2, q1 = s1 >> 2;
    for (int i = q0 + t; i < q1; i += 256) {
        ivec4 c4 = __builtin_nontemporal_load((const ivec4*)col + i);
        ivec4 r4 = __builtin_nontemporal_load((const ivec4*)row + i);
        int p0 = atomicAdd(&curs[c4.x >> 8], 1);
        tmp[p0] = ((unsigned long long)(unsigned)c4.x << 32) | (unsigned)r4.x;
        int p1 = atomicAdd(&curs[c4.y >> 8], 1);
        tmp[p1] = ((unsigned long long)(unsigned)c4.y << 32) | (unsigned)r4.y;
        int p2 = atomicAdd(&curs[c4.z >> 8], 1);
        tmp[p2] = ((unsigned long long)(unsigned)c4.z << 32) | (unsigned)r4.z;
        int p3 = atomicAdd(&curs[c4.w >> 8], 1);
        tmp[p3] = ((unsigned long long)(unsigned)c4.w << 32) | (unsigned)r4.w;
    }
    for (int i = (q1 << 2) + t; i < s1; i += 256) {
        int c = col[i], r = row[i];
        int p = atomicAdd(&curs[c >> 8], 1);
        tmp[p] = ((unsigned long long)(unsigned)c << 32) | (unsigned)r;
    }
}

__global__ __launch_bounds__(256) void bucket_fill(const unsigned long long* __restrict__ tmp,
                                                   const int* __restrict__ bucketStart,
                                                   int* __restrict__ rowPtr,
                                                   float* __restrict__ dinv,
                                                   int* __restrict__ srcList,
                                                   int n) {
    __shared__ int cnt[256];
    __shared__ int cur[256];
    __shared__ int seg[SEGCAP];
    int b = blockIdx.x, t = threadIdx.x;
    int node0 = b << 8;
    int s0 = bucketStart[b], s1 = bucketStart[b + 1];
    int len = s1 - s0;
    cnt[t] = 0;
    __syncthreads();
    for (int i = s0 + t; i < s1; i += 256) {
        int c = (int)(tmp[i] >> 32);
        atomicAdd(&cnt[c - node0], 1);
    }
    __syncthreads();
    int v = cnt[t];
    cur[t] = v;
    __syncthreads();
    for (int d = 1; d < 256; d <<= 1) {
        int add = (t >= d) ? cur[t - d] : 0;
        __syncthreads();
        cur[t] += add;
        __syncthreads();
    }
    int excl = cur[t] - v;
    int node = node0 + t;
    if (node < n) {
        rowPtr[node] = s0 + excl;
        dinv[node] = rsqrtf((float)v + 1.0f);   // +1 self-loop
    }
    cur[t] = excl;
    __syncthreads();
    if (len <= SEGCAP) {
        for (int i = s0 + t; i < s1; i += 256) {
            unsigned long long p = tmp[i];
            int c = (int)(p >> 32);
            int r = (int)(p & 0xffffffffu);
            int pos = atomicAdd(&cur[c - node0], 1);
            seg[pos] = r;
        }
        __syncthreads();
        for (int i = t; i < len; i += 256)
            srcList[s0 + i] = seg[i];
    } else {                                    // overflow fallback (never for this graph)
        for (int i = s0 + t; i < s1; i += 256) {
            unsigned long long p = tmp[i];
            int c = (int)(p >> 32);
            int r = (int)(p & 0xffffffffu);
            int pos = atomicAdd(&cur[c - node0], 1);
            srcList[s0 + pos] = r;
        }
    }
}

// ---------------------------------------------------------------------------
// pack_w_all + head_collapse fused. Blocks 0..191: pack W1/W2/W3 into MFMA
// B-fragment bf16 hi/lo planes. Block 192: Weff = Wp1@Wp2, beff = bp1@Wp2+bp2.
// ---------------------------------------------------------------------------
__global__ __launch_bounds__(256) void pack_w_all(const float* __restrict__ W1,
                                                  const float* __restrict__ W2,
                                                  const float* __restrict__ W3,
                                                  unsigned short* __restrict__ Wq,
                                                  const float* __restrict__ Wp1,
                                                  const float* __restrict__ bp1,
                                                  const float* __restrict__ Wp2,
                                                  const float* __restrict__ bp2,
                                                  float* __restrict__ Weff,
                                                  float* __restrict__ beff) {
    if (blockIdx.x == 192) {                     // head collapse
        __shared__ float w2[384];
        int t = threadIdx.x;
        for (int idx = t; idx < 384; idx += 256) w2[idx] = Wp2[idx];
        __syncthreads();
        if (t < 128) {
            float p0 = 0.f, p1 = 0.f, p2 = 0.f;
            const float* wr = Wp1 + (size_t)t * 128;
            for (int k = 0; k < 128; k++) {
                float v = wr[k];
                p0 += v * w2[k * 3 + 0];
                p1 += v * w2[k * 3 + 1];
                p2 += v * w2[k * 3 + 2];
            }
            Weff[t * 3 + 0] = p0; Weff[t * 3 + 1] = p1; Weff[t * 3 + 2] = p2;
            if (t == 0) {
                float q0 = bp2[0], q1 = bp2[1], q2 = bp2[2];
                for (int k = 0; k < 128; k++) {
                    float v = bp1[k];
                    q0 += v * w2[k * 3 + 0];
                    q1 += v * w2[k * 3 + 1];
                    q2 += v * w2[k * 3 + 2];
                }
                beff[0] = q0; beff[1] = q1; beff[2] = q2;
            }
        }
        return;
    }
    int w = blockIdx.x >> 6;
    const float* W = (w == 0) ? W1 : (w == 1) ? W2 : W3;
    unsigned short* Wp = Wq + (size_t)w * 32768;
    int s = (blockIdx.x & 63) * 256 + threadIdx.x;   // 0..16383
    int i = s & 7;
    int lane = (s >> 3) & 63;
    int jt = (s >> 9) & 7;
    int kb = s >> 12;
    int k = kb * 32 + ((lane >> 4) & 3) * 8 + i;
    int nn = jt * 16 + (lane & 15);
    float v = W[k * 128 + nn];
    __hip_bfloat16 hi = __float2bfloat16(v);
    float hf = __bfloat162float(hi);
    __hip_bfloat16 lo = __float2bfloat16(v - hf);
    Wp[s]         = *(unsigned short*)&hi;
    Wp[16384 + s] = *(unsigned short*)&lo;
}

// ---------------------------------------------------------------------------
// MFMA gemm: 128-row tile, 512 threads (8 waves x 16 rows), B kb-slice staged
// in LDS once for all 8 waves. 3 MFMA per (kb,jt): ah*bh + ah*bl + al*bh.
// ---------------------------------------------------------------------------
__device__ __forceinline__ void split8(const float* __restrict__ p,
                                       bf16x8v& ah, bf16x8v& al) {
#pragma unroll
    for (int i = 0; i < 8; i++) {
        float v = p[i];
        __hip_bfloat16 hb = __float2bfloat16(v);
        float hf = __bfloat162float(hb);
        __hip_bfloat16 lb = __float2bfloat16(v - hf);
        ah[i] = *(short*)&hb;
        al[i] = *(short*)&lb;
    }
}

template<int ASRC>   // 0: f32 A (split in-register), 1: hi/lo bf16 planes
__global__ __launch_bounds__(512) void gemm_mfma(const float* __restrict__ Af32,
                                                 const unsigned short* __restrict__ Ahi,
                                                 const unsigned short* __restrict__ Alo,
                                                 const unsigned short* __restrict__ Wp,
                                                 const float* __restrict__ dinv,
                                                 unsigned short* __restrict__ hbOut,
                                                 int n) {
    __shared__ unsigned short Bs[8192];   // hi[4096] || lo[4096] for one kb-slice

    const int tx = threadIdx.x;
    const int wv = tx >> 6;               // 0..7
    const int l  = tx & 63;
    const int m0 = blockIdx.x * 128 + wv * 16;
    int arow = m0 + (l & 15);
    if (arow >= n) arow = 0;            // clamped rows only affect unstored outputs
    const int kofs = (l >> 4) * 8;

    f32x4v acc[8];
#pragma unroll
    for (int jt = 0; jt < 8; jt++) acc[jt] = (f32x4v){0.f, 0.f, 0.f, 0.f};

#pragma unroll
    for (int kb = 0; kb < 4; kb++) {
        __syncthreads();   // protect previous slice's reads
        {   // stage 4096 hi + 4096 lo ushorts: 8+8 per thread (512 threads)
            *(u16x8*)&Bs[tx * 8]        = *(const u16x8*)(Wp + kb * 4096 + tx * 8);
            *(u16x8*)&Bs[4096 + tx * 8] = *(const u16x8*)(Wp + 16384 + kb * 4096 + tx * 8);
        }
        bf16x8v ah, al;
        if (ASRC == 0) {
            split8(Af32 + (size_t)arow * 128 + kb * 32 + kofs, ah, al);
        } else {
            ah = *(const bf16x8v*)(Ahi + (size_t)arow * 128 + kb * 32 + kofs);
            al = *(const bf16x8v*)(Alo + (size_t)arow * 128 + kb * 32 + kofs);
        }
        __syncthreads();
#pragma unroll
        for (int jt = 0; jt < 8; jt++) {
            bf16x8v bh = *(const bf16x8v*)&Bs[jt * 512 + l * 8];
            bf16x8v bl = *(const bf16x8v*)&Bs[4096 + jt * 512 + l * 8];
            acc[jt] = __builtin_amdgcn_mfma_f32_16x16x32_bf16(ah, bh, acc[jt], 0, 0, 0);
            acc[jt] = __builtin_amdgcn_mfma_f32_16x16x32_bf16(ah, bl, acc[jt], 0, 0, 0);
            acc[jt] = __builtin_amdgcn_mfma_f32_16x16x32_bf16(al, bh, acc[jt], 0, 0, 0);
        }
    }

    const int r0 = m0 + (l >> 4) * 4;
    const int colb = l & 15;
#pragma unroll
    for (int r = 0; r < 4; r++) {
        int grow = r0 + r;
        if (grow < n) {
            float dv = dinv[grow];
#pragma unroll
            for (int jt = 0; jt < 8; jt++) {
                __hip_bfloat16 t = __float2bfloat16(acc[jt][r] * dv);
                hbOut[(size_t)grow * 128 + jt * 16 + colb] = *(unsigned short*)&t;
            }
        }
    }
}

#define BF_LO(u) __uint_as_float((u) << 16)
#define BF_HI(u) __uint_as_float((u) & 0xffff0000u)

#define ACC8(u)  do { \
    a[0] += BF_LO((u).x); a[1] += BF_HI((u).x); \
    a[2] += BF_LO((u).y); a[3] += BF_HI((u).y); \
    a[4] += BF_LO((u).z); a[5] += BF_HI((u).z); \
    a[6] += BF_LO((u).w); a[7] += BF_HI((u).w); } while (0)

// ---------------------------------------------------------------------------
// agg_post (LN layers): 8-edge unrolled gather (R28 structure, 24 VGPR);
// output = hi/lo bf16 planes.
// ---------------------------------------------------------------------------
__global__ __launch_bounds__(128) void agg_post(const unsigned int* __restrict__ hb,
                                                const int* __restrict__ rowPtr,
                                                const int* __restrict__ srcList,
                                                const float* __restrict__ dinv,
                                                const float* __restrict__ b,
                                                const float* __restrict__ g,
                                                const float* __restrict__ beta,
                                                unsigned short* __restrict__ outHi,
                                                unsigned short* __restrict__ outLo,
                                                int n) {
    int wid = (blockIdx.x * 128 + threadIdx.x) >> 6;
    int lane = threadIdx.x & 63;
    if (wid >= n) return;
    int h = lane & 15;
    int gg = lane >> 4;
    int e0 = rowPtr[wid], e1 = rowPtr[wid + 1];
    float dc = dinv[wid];
    const uint4* hb4 = (const uint4*)hb;

    uint4 us = hb4[(size_t)wid * 16 + h];

    float a[8];
#pragma unroll
    for (int j = 0; j < 8; j++) a[j] = 0.f;

    int idx0 = (e0 + gg < e1) ? srcList[e0 + gg] : -1;
    int idx1 = (e0 + 4 + gg < e1) ? srcList[e0 + 4 + gg] : -1;
    int e = e0;
    for (; e + 8 <= e1; e += 8) {
        int ni0 = (e + 8 + gg < e1) ? srcList[e + 8 + gg] : -1;
        int ni1 = (e + 12 + gg < e1) ? srcList[e + 12 + gg] : -1;
        uint4 u0 = hb4[(size_t)idx0 * 16 + h];
        uint4 u1 = hb4[(size_t)idx1 * 16 + h];
        ACC8(u0); ACC8(u1);
        idx0 = ni0; idx1 = ni1;
    }
    if (idx0 >= 0) { uint4 u = hb4[(size_t)idx0 * 16 + h]; ACC8(u); }
    if (idx1 >= 0) { uint4 u = hb4[(size_t)idx1 * 16 + h]; ACC8(u); }

#pragma unroll
    for (int j = 0; j < 8; j++) {
        a[j] += __shfl_xor(a[j], 16, 64);
        a[j] += __shfl_xor(a[j], 32, 64);
    }
    ACC8(us);   // self-loop, same dc scaling as gather terms

    float4 bv0 = *(const float4*)(b + h * 8);
    float4 bv1 = *(const float4*)(b + h * 8 + 4);
    a[0] = fmaxf(a[0] * dc + bv0.x, 0.f);
    a[1] = fmaxf(a[1] * dc + bv0.y, 0.f);
    a[2] = fmaxf(a[2] * dc + bv0.z, 0.f);
    a[3] = fmaxf(a[3] * dc + bv0.w, 0.f);
    a[4] = fmaxf(a[4] * dc + bv1.x, 0.f);
    a[5] = fmaxf(a[5] * dc + bv1.y, 0.f);
    a[6] = fmaxf(a[6] * dc + bv1.z, 0.f);
    a[7] = fmaxf(a[7] * dc + bv1.w, 0.f);

    float s = ((a[0] + a[1]) + (a[2] + a[3])) + ((a[4] + a[5]) + (a[6] + a[7]));
#pragma unroll
    for (int m = 8; m >= 1; m >>= 1) s += __shfl_xor(s, m, 64);
    float mu = s * (1.f / 128.f);
    float sq = 0.f;
    float d[8];
#pragma unroll
    for (int j = 0; j < 8; j++) { d[j] = a[j] - mu; sq += d[j] * d[j]; }
#pragma unroll
    for (int m = 8; m >= 1; m >>= 1) sq += __shfl_xor(sq, m, 64);
    float rs = rsqrtf(sq * (1.f / 128.f) + EPS_LN);
    float4 gv0 = *(const float4*)(g + h * 8);
    float4 gv1 = *(const float4*)(g + h * 8 + 4);
    float4 bt0 = *(const float4*)(beta + h * 8);
    float4 bt1 = *(const float4*)(beta + h * 8 + 4);
    a[0] = d[0] * rs * gv0.x + bt0.x;
    a[1] = d[1] * rs * gv0.y + bt0.y;
    a[2] = d[2] * rs * gv0.z + bt0.z;
    a[3] = d[3] * rs * gv0.w + bt0.w;
    a[4] = d[4] * rs * gv1.x + bt1.x;
    a[5] = d[5] * rs * gv1.y + bt1.y;
    a[6] = d[6] * rs * gv1.z + bt1.z;
    a[7] = d[7] * rs * gv1.w + bt1.w;

    if (gg == 0) {
        ushort4 h0, h1, l0, l1;
        __hip_bfloat16 bb; float ff;
        bb = __float2bfloat16(a[0]); ff = __bfloat162float(bb); h0.x = *(unsigned short*)&bb;
        bb = __float2bfloat16(a[0] - ff); l0.x = *(unsigned short*)&bb;
        bb = __float2bfloat16(a[1]); ff = __bfloat162float(bb); h0.y = *(unsigned short*)&bb;
        bb = __float2bfloat16(a[1] - ff); l0.y = *(unsigned short*)&bb;
        bb = __float2bfloat16(a[2]); ff = __bfloat162float(bb); h0.z = *(unsigned short*)&bb;
        bb = __float2bfloat16(a[2] - ff); l0.z = *(unsigned short*)&bb;
        bb = __float2bfloat16(a[3]); ff = __bfloat162float(bb); h0.w = *(unsigned short*)&bb;
        bb = __float2bfloat16(a[3] - ff); l0.w = *(unsigned short*)&bb;
        bb = __float2bfloat16(a[4]); ff = __bfloat162float(bb); h1.x = *(unsigned short*)&bb;
        bb = __float2bfloat16(a[4] - ff); l1.x = *(unsigned short*)&bb;
        bb = __float2bfloat16(a[5]); ff = __bfloat162float(bb); h1.y = *(unsigned short*)&bb;
        bb = __float2bfloat16(a[5] - ff); l1.y = *(unsigned short*)&bb;
        bb = __float2bfloat16(a[6]); ff = __bfloat162float(bb); h1.z = *(unsigned short*)&bb;
        bb = __float2bfloat16(a[6] - ff); l1.z = *(unsigned short*)&bb;
        bb = __float2bfloat16(a[7]); ff = __bfloat162float(bb); h1.w = *(unsigned short*)&bb;
        bb = __float2bfloat16(a[7] - ff); l1.w = *(unsigned short*)&bb;
        size_t base = (size_t)wid * 128 + h * 8;
        *(ushort4*)(outHi + base)     = h0;
        *(ushort4*)(outHi + base + 4) = h1;
        *(ushort4*)(outLo + base)     = l0;
        *(ushort4*)(outLo + base + 4) = l1;
    }
}

// ---------------------------------------------------------------------------
// Fused layer-3 agg (relu, no LN) + collapsed head. Head weights loaded into
// registers AFTER the gather loop (low peak VGPR). No LDS.
// ---------------------------------------------------------------------------
__global__ __launch_bounds__(128) void agg_head(
        const unsigned int* __restrict__ hb,
        const int* __restrict__ rowPtr,
        const int* __restrict__ srcList,
        const float* __restrict__ dinv,
        const float* __restrict__ b,
        const float* __restrict__ Weff,
        const float* __restrict__ beff,
        float* __restrict__ out, int n) {
    int tt = threadIdx.x;
    int wid = (blockIdx.x * 128 + tt) >> 6;
    int lane = tt & 63;
    if (wid >= n) return;
    int h = lane & 15;
    int gg = lane >> 4;
    int e0 = rowPtr[wid], e1 = rowPtr[wid + 1];
    float dc = dinv[wid];
    const uint4* hb4 = (const uint4*)hb;
    uint4 us = hb4[(size_t)wid * 16 + h];

    float a[8];
#pragma unroll
    for (int j = 0; j < 8; j++) a[j] = 0.f;

    int idx0 = (e0 + gg < e1) ? srcList[e0 + gg] : -1;
    int idx1 = (e0 + 4 + gg < e1) ? srcList[e0 + 4 + gg] : -1;
    int e = e0;
    for (; e + 8 <= e1; e += 8) {
        int ni0 = (e + 8 + gg < e1) ? srcList[e + 8 + gg] : -1;
        int ni1 = (e + 12 + gg < e1) ? srcList[e + 12 + gg] : -1;
        uint4 u0 = hb4[(size_t)idx0 * 16 + h];
        uint4 u1 = hb4[(size_t)idx1 * 16 + h];
        ACC8(u0); ACC8(u1);
        idx0 = ni0; idx1 = ni1;
    }
    if (idx0 >= 0) { uint4 u = hb4[(size_t)idx0 * 16 + h]; ACC8(u); }
    if (idx1 >= 0) { uint4 u = hb4[(size_t)idx1 * 16 + h]; ACC8(u); }

#pragma unroll
    for (int j = 0; j < 8; j++) {
        a[j] += __shfl_xor(a[j], 16, 64);
        a[j] += __shfl_xor(a[j], 32, 64);
    }
    ACC8(us);

    float4 bv0 = *(const float4*)(b + h * 8);
    float4 bv1 = *(const float4*)(b + h * 8 + 4);
    a[0] = fmaxf(a[0] * dc + bv0.x, 0.f);
    a[1] = fmaxf(a[1] * dc + bv0.y, 0.f);
    a[2] = fmaxf(a[2] * dc + bv0.z, 0.f);
    a[3] = fmaxf(a[3] * dc + bv0.w, 0.f);
    a[4] = fmaxf(a[4] * dc + bv1.x, 0.f);
    a[5] = fmaxf(a[5] * dc + bv1.y, 0.f);
    a[6] = fmaxf(a[6] * dc + bv1.z, 0.f);
    a[7] = fmaxf(a[7] * dc + bv1.w, 0.f);

    // head weights loaded AFTER gather (gather regs dead): 6x float4
    float p0 = 0.f, p1 = 0.f, p2 = 0.f;
    {
        const float4* wp = (const float4*)(Weff + 24 * h);
#pragma unroll
        for (int q = 0; q < 2; q++) {
            float4 w0 = wp[3 * q + 0];
            float4 w1 = wp[3 * q + 1];
            float4 w2 = wp[3 * q + 2];
            const float* aw = &a[4 * q];
            p0 += aw[0] * w0.x + aw[1] * w0.w + aw[2] * w1.z + aw[3] * w2.y;
            p1 += aw[0] * w0.y + aw[1] * w1.x + aw[2] * w1.w + aw[3] * w2.z;
            p2 += aw[0] * w0.z + aw[1] * w1.y + aw[2] * w2.x + aw[3] * w2.w;
        }
    }
#pragma unroll
    for (int m = 8; m >= 1; m >>= 1) {
        p0 += __shfl_xor(p0, m, 64);
        p1 += __shfl_xor(p1, m, 64);
        p2 += __shfl_xor(p2, m, 64);
    }
    if (lane == 0) {
        out[(size_t)wid * 3 + 0] = p0 + beff[0];
        out[(size_t)wid * 3 + 1] = p1 + beff[1];
        out[(size_t)wid * 3 + 2] = p2 + beff[2];
    }
}

// ---------------------------------------------------------------------------
extern "C" void kernel_launch(void* const* d_in, const int* in_sizes, int n_in,
                              void* d_out, int out_size, void* d_ws, size_t ws_size,
                              hipStream_t stream) {
    const float* x   = (const float*)d_in[0];
    const int* ei    = (const int*)d_in[1];
    const float* W1  = (const float*)d_in[2];
    const float* b1  = (const float*)d_in[3];
    const float* W2  = (const float*)d_in[4];
    const float* b2  = (const float*)d_in[5];
    const float* W3  = (const float*)d_in[6];
    const float* b3  = (const float*)d_in[7];
    const float* g1  = (const float*)d_in[8];
    const float* be1 = (const float*)d_in[9];
    const float* g2  = (const float*)d_in[10];
    const float* be2 = (const float*)d_in[11];
    const float* Wp1f = (const float*)d_in[12];
    const float* bp1 = (const float*)d_in[13];
    const float* Wp2f = (const float*)d_in[14];
    const float* bp2 = (const float*)d_in[15];
    float* out = (float*)d_out;

    const int n = in_sizes[0] / 128;   // 50000
    const int E = in_sizes[1] / 2;     // 1600000
    const int* row = ei;
    const int* col = ei + E;

    char* ws = (char*)d_ws;
    size_t nA  = ((size_t)n * 4 + 255) & ~(size_t)255;
    size_t nA1 = ((size_t)(n + 1) * 4 + 255) & ~(size_t)255;
    size_t eA  = ((size_t)E * 4 + 255) & ~(size_t)255;
    size_t hbSz = ((size_t)n * 128 * 2 + 255) & ~(size_t)255;
    int*   rowPtr  = (int*)ws;
    float* dinvp   = (float*)(ws + nA1);
    int*   srcList = (int*)(ws + nA1 + nA);
    unsigned short* hbA = (unsigned short*)(ws + nA1 + nA + eA);
    unsigned short* hbB = hbA + hbSz / 2;
    unsigned short* Phi = hbB + hbSz / 2;
    unsigned short* Plo = Phi + hbSz / 2;
    unsigned short* Wq  = Plo + hbSz / 2;        // 3 x 32768 ushorts
    float* Weff = (float*)(Wq + 3 * 32768);
    float* beff = Weff + 384;
    // CSR scratch aliases Phi/Plo (consumed by bucket_fill before agg writes):
    unsigned long long* tmp = (unsigned long long*)Phi;
    int* chunkBH     = (int*)((char*)Phi + 2 * eA);
    int* bucketStart = (int*)((char*)Phi + 2 * eA + (size_t)NB * 256 * 4);

    const int nbuck = (n + 255) >> 8;                 // 196
    const int per   = (((E + NB - 1) / NB) + 15) & ~15;
    const int tileBlocks = (n + 127) / 128;           // 391
    const int nodeWaveBlocks = (n + 1) / 2;           // 25000

    // CSR build (bucketed counting sort, zero global atomics)
    bucket_hist<<<NB, 256, 0, stream>>>(col, chunkBH, E, per, nbuck);
    bucket_scan<<<1, 256, 0, stream>>>(chunkBH, bucketStart, rowPtr, E, n, nbuck, NB);
    scatter_pairs<<<NB, 256, 0, stream>>>(row, col, chunkBH, bucketStart, tmp, E, per, nbuck);
    bucket_fill<<<nbuck, 256, 0, stream>>>(tmp, bucketStart, rowPtr, dinvp, srcList, n);
    pack_w_all<<<193, 256, 0, stream>>>(W1, W2, W3, Wq, Wp1f, bp1, Wp2f, bp2, Weff, beff);

    // ---- layer 1 (x f32 -> in-register hi/lo split) ----
    gemm_mfma<0><<<tileBlocks, 512, 0, stream>>>(x, nullptr, nullptr, Wq, dinvp, hbA, n);
    agg_post<<<nodeWaveBlocks, 128, 0, stream>>>((const unsigned int*)hbA,
                                                 rowPtr, srcList, dinvp,
                                                 b1, g1, be1, Phi, Plo, n);
    // ---- layer 2 ----
    gemm_mfma<1><<<tileBlocks, 512, 0, stream>>>(nullptr, Phi, Plo, Wq + 32768, dinvp, hbB, n);
    agg_post<<<nodeWaveBlocks, 128, 0, stream>>>((const unsigned int*)hbB,
                                                 rowPtr, srcList, dinvp,
                                                 b2, g2, be2, Phi, Plo, n);
    // ---- layer 3 ----
    gemm_mfma<1><<<tileBlocks, 512, 0, stream>>>(nullptr, Phi, Plo, Wq + 65536, dinvp, hbA, n);
    agg_head<<<nodeWaveBlocks, 128, 0, stream>>>((const unsigned int*)hbA,
                                                 rowPtr, srcList, dinvp,
                                                 b3, Weff, beff, out, n);
}

// Round 14
// 354.259 us; speedup vs baseline: 1.3180x; 1.0063x over previous
//
#include <hip/hip_runtime.h>
#include <hip/hip_bf16.h>

#define EPS_LN 1e-5f
#define NB    256             // edge chunks for hist/scatter
#define SEGCAP 16384          // srcList segment capacity per bucket (64KB LDS)

typedef int ivec4 __attribute__((ext_vector_type(4)));
typedef short bf16x8v __attribute__((ext_vector_type(8)));
typedef float f32x4v __attribute__((ext_vector_type(4)));
typedef unsigned short u16x8 __attribute__((ext_vector_type(8)));

// ===========================================================================
// R34: barrier-free gemm K-loop + packed CSR pairs, on R33 (356.5us).
//  - gemm_mfma: stage the ENTIRE packed W (64KB hi+lo) in LDS once ->
//    ONE __syncthreads per block (was 8). K-loop = pure MFMA + LDS reads,
//    all A-loads in flight. 2 blocks/CU at 64KB LDS.
//  - scatter_pairs/bucket_fill: pairs packed to uint32 ((c&255)<<24 | r;
//    r<2^17, bucket known) -> halves pair write+read (12.8->6.4MB each way).
//  - aggs unchanged (at their random-fetch HBM floor, ~55us each).
// ===========================================================================

__global__ __launch_bounds__(256) void bucket_hist(const int* __restrict__ col,
                                                   int* __restrict__ chunkBH,
                                                   int E, int per, int nbuck) {
    __shared__ int hist[256];
    int t = threadIdx.x;
    hist[t] = 0;
    __syncthreads();
    int s0 = blockIdx.x * per;
    int s1 = s0 + per; if (s1 > E) s1 = E;
    if (s0 < s1) {
        int q0 = s0 >> 2, q1 = s1 >> 2;
        for (int i = q0 + t; i < q1; i += 256) {
            ivec4 c = __builtin_nontemporal_load((const ivec4*)col + i);
            atomicAdd(&hist[c.x >> 8], 1);
            atomicAdd(&hist[c.y >> 8], 1);
            atomicAdd(&hist[c.z >> 8], 1);
            atomicAdd(&hist[c.w >> 8], 1);
        }
        for (int i = (q1 << 2) + t; i < s1; i += 256)
            atomicAdd(&hist[col[i] >> 8], 1);
    }
    __syncthreads();
    if (t < nbuck) chunkBH[blockIdx.x * 256 + t] = hist[t];   // [k][b], coalesced
}

__global__ __launch_bounds__(256) void bucket_scan(int* __restrict__ chunkBH,
                                                   int* __restrict__ bucketStart,
                                                   int* __restrict__ rowPtr,
                                                   int E, int n, int nbuck, int nb) {
    __shared__ int tot[256];
    int t = threadIdx.x;
    int run = 0;
    if (t < nbuck) {
        for (int k0 = 0; k0 < nb; k0 += 16) {
            int v[16];
#pragma unroll
            for (int j = 0; j < 16; j++)
                v[j] = (k0 + j < nb) ? chunkBH[(k0 + j) * 256 + t] : 0;
#pragma unroll
            for (int j = 0; j < 16; j++) {
                int tv = v[j];
                if (k0 + j < nb) chunkBH[(k0 + j) * 256 + t] = run;
                run += tv;
            }
        }
    }
    tot[t] = run;
    __syncthreads();
    for (int d = 1; d < 256; d <<= 1) {
        int add = (t >= d) ? tot[t - d] : 0;
        __syncthreads();
        tot[t] += add;
        __syncthreads();
    }
    if (t < nbuck) bucketStart[t] = tot[t] - run;
    if (t == 0) { bucketStart[nbuck] = E; rowPtr[n] = E; }
}

__global__ __launch_bounds__(256) void scatter_pairs(const int* __restrict__ row,
                                                     const int* __restrict__ col,
                                                     const int* __restrict__ chunkBH,
                                                     const int* __restrict__ bucketStart,
                                                     unsigned int* __restrict__ tmp,
                                                     int E, int per, int nbuck) {
    __shared__ int curs[256];
    int t = threadIdx.x;
    int k = blockIdx.x;
    curs[t] = (t < nbuck) ? (chunkBH[k * 256 + t] + bucketStart[t]) : 0;
    __syncthreads();
    int s0 = k * per;
    int s1 = s0 + per; if (s1 > E) s1 = E;
    if (s0 >= s1) return;
    int q0 = s0 >> 2, q1 = s1 >> 2;
    for (int i = q0 + t; i < q1; i += 256) {
        ivec4 c4 = __builtin_nontemporal_load((const ivec4*)col + i);
        ivec4 r4 = __builtin_nontemporal_load((const ivec4*)row + i);
        int p0 = atomicAdd(&curs[c4.x >> 8], 1);
        tmp[p0] = ((unsigned)(c4.x & 255) << 24) | (unsigned)r4.x;
        int p1 = atomicAdd(&curs[c4.y >> 8], 1);
        tmp[p1] = ((unsigned)(c4.y & 255) << 24) | (unsigned)r4.y;
        int p2 = atomicAdd(&curs[c4.z >> 8], 1);
        tmp[p2] = ((unsigned)(c4.z & 255) << 24) | (unsigned)r4.z;
        int p3 = atomicAdd(&curs[c4.w >> 8], 1);
        tmp[p3] = ((unsigned)(c4.w & 255) << 24) | (unsigned)r4.w;
    }
    for (int i = (q1 << 2) + t; i < s1; i += 256) {
        int c = col[i], r = row[i];
        int p = atomicAdd(&curs[c >> 8], 1);
        tmp[p] = ((unsigned)(c & 255) << 24) | (unsigned)r;
    }
}

__global__ __launch_bounds__(256) void bucket_fill(const unsigned int* __restrict__ tmp,
                                                   const int* __restrict__ bucketStart,
                                                   int* __restrict__ rowPtr,
                                                   float* __restrict__ dinv,
                                                   int* __restrict__ srcList,
                                                   int n) {
    __shared__ int cnt[256];
    __shared__ int cur[256];
    __shared__ int seg[SEGCAP];
    int b = blockIdx.x, t = threadIdx.x;
    int node0 = b << 8;
    int s0 = bucketStart[b], s1 = bucketStart[b + 1];
    int len = s1 - s0;
    cnt[t] = 0;
    __syncthreads();
    for (int i = s0 + t; i < s1; i += 256) {
        atomicAdd(&cnt[tmp[i] >> 24], 1);
    }
    __syncthreads();
    int v = cnt[t];
    cur[t] = v;
    __syncthreads();
    for (int d = 1; d < 256; d <<= 1) {
        int add = (t >= d) ? cur[t - d] : 0;
        __syncthreads();
        cur[t] += add;
        __syncthreads();
    }
    int excl = cur[t] - v;
    int node = node0 + t;
    if (node < n) {
        rowPtr[node] = s0 + excl;
        dinv[node] = rsqrtf((float)v + 1.0f);   // +1 self-loop
    }
    cur[t] = excl;
    __syncthreads();
    if (len <= SEGCAP) {
        for (int i = s0 + t; i < s1; i += 256) {
            unsigned int p = tmp[i];
            int pos = atomicAdd(&cur[p >> 24], 1);
            seg[pos] = (int)(p & 0xffffffu);
        }
        __syncthreads();
        for (int i = t; i < len; i += 256)
            srcList[s0 + i] = seg[i];
    } else {                                    // overflow fallback (never for this graph)
        for (int i = s0 + t; i < s1; i += 256) {
            unsigned int p = tmp[i];
            int pos = atomicAdd(&cur[p >> 24], 1);
            srcList[s0 + pos] = (int)(p & 0xffffffu);
        }
    }
}

// ---------------------------------------------------------------------------
// pack_w_all + head_collapse fused. Blocks 0..191: pack W1/W2/W3 into MFMA
// B-fragment bf16 hi/lo planes. Block 192: Weff = Wp1@Wp2, beff = bp1@Wp2+bp2.
// ---------------------------------------------------------------------------
__global__ __launch_bounds__(256) void pack_w_all(const float* __restrict__ W1,
                                                  const float* __restrict__ W2,
                                                  const float* __restrict__ W3,
                                                  unsigned short* __restrict__ Wq,
                                                  const float* __restrict__ Wp1,
                                                  const float* __restrict__ bp1,
                                                  const float* __restrict__ Wp2,
                                                  const float* __restrict__ bp2,
                                                  float* __restrict__ Weff,
                                                  float* __restrict__ beff) {
    if (blockIdx.x == 192) {                     // head collapse
        __shared__ float w2[384];
        int t = threadIdx.x;
        for (int idx = t; idx < 384; idx += 256) w2[idx] = Wp2[idx];
        __syncthreads();
        if (t < 128) {
            float p0 = 0.f, p1 = 0.f, p2 = 0.f;
            const float* wr = Wp1 + (size_t)t * 128;
            for (int k = 0; k < 128; k++) {
                float v = wr[k];
                p0 += v * w2[k * 3 + 0];
                p1 += v * w2[k * 3 + 1];
                p2 += v * w2[k * 3 + 2];
            }
            Weff[t * 3 + 0] = p0; Weff[t * 3 + 1] = p1; Weff[t * 3 + 2] = p2;
            if (t == 0) {
                float q0 = bp2[0], q1 = bp2[1], q2 = bp2[2];
                for (int k = 0; k < 128; k++) {
                    float v = bp1[k];
                    q0 += v * w2[k * 3 + 0];
                    q1 += v * w2[k * 3 + 1];
                    q2 += v * w2[k * 3 + 2];
                }
                beff[0] = q0; beff[1] = q1; beff[2] = q2;
            }
        }
        return;
    }
    int w = blockIdx.x >> 6;
    const float* W = (w == 0) ? W1 : (w == 1) ? W2 : W3;
    unsigned short* Wp = Wq + (size_t)w * 32768;
    int s = (blockIdx.x & 63) * 256 + threadIdx.x;   // 0..16383
    int i = s & 7;
    int lane = (s >> 3) & 63;
    int jt = (s >> 9) & 7;
    int kb = s >> 12;
    int k = kb * 32 + ((lane >> 4) & 3) * 8 + i;
    int nn = jt * 16 + (lane & 15);
    float v = W[k * 128 + nn];
    __hip_bfloat16 hi = __float2bfloat16(v);
    float hf = __bfloat162float(hi);
    __hip_bfloat16 lo = __float2bfloat16(v - hf);
    Wp[s]         = *(unsigned short*)&hi;
    Wp[16384 + s] = *(unsigned short*)&lo;
}

// ---------------------------------------------------------------------------
// MFMA gemm: 128-row tile, 512 threads (8 waves x 16 rows). ENTIRE packed W
// (64KB hi+lo) staged in LDS once -> ONE barrier; K-loop barrier-free.
// 3 MFMA per (kb,jt): ah*bh + ah*bl + al*bh (~f32 precision).
// ---------------------------------------------------------------------------
__device__ __forceinline__ void split8(const float* __restrict__ p,
                                       bf16x8v& ah, bf16x8v& al) {
#pragma unroll
    for (int i = 0; i < 8; i++) {
        float v = p[i];
        __hip_bfloat16 hb = __float2bfloat16(v);
        float hf = __bfloat162float(hb);
        __hip_bfloat16 lb = __float2bfloat16(v - hf);
        ah[i] = *(short*)&hb;
        al[i] = *(short*)&lb;
    }
}

template<int ASRC>   // 0: f32 A (split in-register), 1: hi/lo bf16 planes
__global__ __launch_bounds__(512) void gemm_mfma(const float* __restrict__ Af32,
                                                 const unsigned short* __restrict__ Ahi,
                                                 const unsigned short* __restrict__ Alo,
                                                 const unsigned short* __restrict__ Wp,
                                                 const float* __restrict__ dinv,
                                                 unsigned short* __restrict__ hbOut,
                                                 int n) {
    __shared__ unsigned short Bs[32768];  // full W: hi[16384] || lo[16384]

    const int tx = threadIdx.x;
    const int wv = tx >> 6;               // 0..7
    const int l  = tx & 63;
    const int m0 = blockIdx.x * 128 + wv * 16;
    int arow = m0 + (l & 15);
    if (arow >= n) arow = 0;            // clamped rows only affect unstored outputs
    const int kofs = (l >> 4) * 8;

    // stage full W: 512 threads x 8 chunks x 16B = 64KB, coalesced
#pragma unroll
    for (int i = 0; i < 8; i++)
        *(u16x8*)&Bs[tx * 8 + i * 4096] = *(const u16x8*)(Wp + tx * 8 + i * 4096);

    f32x4v acc[8];
#pragma unroll
    for (int jt = 0; jt < 8; jt++) acc[jt] = (f32x4v){0.f, 0.f, 0.f, 0.f};

    __syncthreads();                      // the only barrier

#pragma unroll
    for (int kb = 0; kb < 4; kb++) {
        bf16x8v ah, al;
        if (ASRC == 0) {
            split8(Af32 + (size_t)arow * 128 + kb * 32 + kofs, ah, al);
        } else {
            ah = *(const bf16x8v*)(Ahi + (size_t)arow * 128 + kb * 32 + kofs);
            al = *(const bf16x8v*)(Alo + (size_t)arow * 128 + kb * 32 + kofs);
        }
#pragma unroll
        for (int jt = 0; jt < 8; jt++) {
            bf16x8v bh = *(const bf16x8v*)&Bs[kb * 4096 + jt * 512 + l * 8];
            bf16x8v bl = *(const bf16x8v*)&Bs[16384 + kb * 4096 + jt * 512 + l * 8];
            acc[jt] = __builtin_amdgcn_mfma_f32_16x16x32_bf16(ah, bh, acc[jt], 0, 0, 0);
            acc[jt] = __builtin_amdgcn_mfma_f32_16x16x32_bf16(ah, bl, acc[jt], 0, 0, 0);
            acc[jt] = __builtin_amdgcn_mfma_f32_16x16x32_bf16(al, bh, acc[jt], 0, 0, 0);
        }
    }

    const int r0 = m0 + (l >> 4) * 4;
    const int colb = l & 15;
#pragma unroll
    for (int r = 0; r < 4; r++) {
        int grow = r0 + r;
        if (grow < n) {
            float dv = dinv[grow];
#pragma unroll
            for (int jt = 0; jt < 8; jt++) {
                __hip_bfloat16 t = __float2bfloat16(acc[jt][r] * dv);
                hbOut[(size_t)grow * 128 + jt * 16 + colb] = *(unsigned short*)&t;
            }
        }
    }
}

#define BF_LO(u) __uint_as_float((u) << 16)
#define BF_HI(u) __uint_as_float((u) & 0xffff0000u)

#define ACC8(u)  do { \
    a[0] += BF_LO((u).x); a[1] += BF_HI((u).x); \
    a[2] += BF_LO((u).y); a[3] += BF_HI((u).y); \
    a[4] += BF_LO((u).z); a[5] += BF_HI((u).z); \
    a[6] += BF_LO((u).w); a[7] += BF_HI((u).w); } while (0)

// ---------------------------------------------------------------------------
// agg_post (LN layers): 8-edge unrolled gather (24 VGPR, 70% occ);
// output = hi/lo bf16 planes.
// ---------------------------------------------------------------------------
__global__ __launch_bounds__(128) void agg_post(const unsigned int* __restrict__ hb,
                                                const int* __restrict__ rowPtr,
                                                const int* __restrict__ srcList,
                                                const float* __restrict__ dinv,
                                                const float* __restrict__ b,
                                                const float* __restrict__ g,
                                                const float* __restrict__ beta,
                                                unsigned short* __restrict__ outHi,
                                                unsigned short* __restrict__ outLo,
                                                int n) {
    int wid = (blockIdx.x * 128 + threadIdx.x) >> 6;
    int lane = threadIdx.x & 63;
    if (wid >= n) return;
    int h = lane & 15;
    int gg = lane >> 4;
    int e0 = rowPtr[wid], e1 = rowPtr[wid + 1];
    float dc = dinv[wid];
    const uint4* hb4 = (const uint4*)hb;

    uint4 us = hb4[(size_t)wid * 16 + h];

    float a[8];
#pragma unroll
    for (int j = 0; j < 8; j++) a[j] = 0.f;

    int idx0 = (e0 + gg < e1) ? srcList[e0 + gg] : -1;
    int idx1 = (e0 + 4 + gg < e1) ? srcList[e0 + 4 + gg] : -1;
    int e = e0;
    for (; e + 8 <= e1; e += 8) {
        int ni0 = (e + 8 + gg < e1) ? srcList[e + 8 + gg] : -1;
        int ni1 = (e + 12 + gg < e1) ? srcList[e + 12 + gg] : -1;
        uint4 u0 = hb4[(size_t)idx0 * 16 + h];
        uint4 u1 = hb4[(size_t)idx1 * 16 + h];
        ACC8(u0); ACC8(u1);
        idx0 = ni0; idx1 = ni1;
    }
    if (idx0 >= 0) { uint4 u = hb4[(size_t)idx0 * 16 + h]; ACC8(u); }
    if (idx1 >= 0) { uint4 u = hb4[(size_t)idx1 * 16 + h]; ACC8(u); }

#pragma unroll
    for (int j = 0; j < 8; j++) {
        a[j] += __shfl_xor(a[j], 16, 64);
        a[j] += __shfl_xor(a[j], 32, 64);
    }
    ACC8(us);   // self-loop, same dc scaling as gather terms

    float4 bv0 = *(const float4*)(b + h * 8);
    float4 bv1 = *(const float4*)(b + h * 8 + 4);
    a[0] = fmaxf(a[0] * dc + bv0.x, 0.f);
    a[1] = fmaxf(a[1] * dc + bv0.y, 0.f);
    a[2] = fmaxf(a[2] * dc + bv0.z, 0.f);
    a[3] = fmaxf(a[3] * dc + bv0.w, 0.f);
    a[4] = fmaxf(a[4] * dc + bv1.x, 0.f);
    a[5] = fmaxf(a[5] * dc + bv1.y, 0.f);
    a[6] = fmaxf(a[6] * dc + bv1.z, 0.f);
    a[7] = fmaxf(a[7] * dc + bv1.w, 0.f);

    float s = ((a[0] + a[1]) + (a[2] + a[3])) + ((a[4] + a[5]) + (a[6] + a[7]));
#pragma unroll
    for (int m = 8; m >= 1; m >>= 1) s += __shfl_xor(s, m, 64);
    float mu = s * (1.f / 128.f);
    float sq = 0.f;
    float d[8];
#pragma unroll
    for (int j = 0; j < 8; j++) { d[j] = a[j] - mu; sq += d[j] * d[j]; }
#pragma unroll
    for (int m = 8; m >= 1; m >>= 1) sq += __shfl_xor(sq, m, 64);
    float rs = rsqrtf(sq * (1.f / 128.f) + EPS_LN);
    float4 gv0 = *(const float4*)(g + h * 8);
    float4 gv1 = *(const float4*)(g + h * 8 + 4);
    float4 bt0 = *(const float4*)(beta + h * 8);
    float4 bt1 = *(const float4*)(beta + h * 8 + 4);
    a[0] = d[0] * rs * gv0.x + bt0.x;
    a[1] = d[1] * rs * gv0.y + bt0.y;
    a[2] = d[2] * rs * gv0.z + bt0.z;
    a[3] = d[3] * rs * gv0.w + bt0.w;
    a[4] = d[4] * rs * gv1.x + bt1.x;
    a[5] = d[5] * rs * gv1.y + bt1.y;
    a[6] = d[6] * rs * gv1.z + bt1.z;
    a[7] = d[7] * rs * gv1.w + bt1.w;

    if (gg == 0) {
        ushort4 h0, h1, l0, l1;
        __hip_bfloat16 bb; float ff;
        bb = __float2bfloat16(a[0]); ff = __bfloat162float(bb); h0.x = *(unsigned short*)&bb;
        bb = __float2bfloat16(a[0] - ff); l0.x = *(unsigned short*)&bb;
        bb = __float2bfloat16(a[1]); ff = __bfloat162float(bb); h0.y = *(unsigned short*)&bb;
        bb = __float2bfloat16(a[1] - ff); l0.y = *(unsigned short*)&bb;
        bb = __float2bfloat16(a[2]); ff = __bfloat162float(bb); h0.z = *(unsigned short*)&bb;
        bb = __float2bfloat16(a[2] - ff); l0.z = *(unsigned short*)&bb;
        bb = __float2bfloat16(a[3]); ff = __bfloat162float(bb); h0.w = *(unsigned short*)&bb;
        bb = __float2bfloat16(a[3] - ff); l0.w = *(unsigned short*)&bb;
        bb = __float2bfloat16(a[4]); ff = __bfloat162float(bb); h1.x = *(unsigned short*)&bb;
        bb = __float2bfloat16(a[4] - ff); l1.x = *(unsigned short*)&bb;
        bb = __float2bfloat16(a[5]); ff = __bfloat162float(bb); h1.y = *(unsigned short*)&bb;
        bb = __float2bfloat16(a[5] - ff); l1.y = *(unsigned short*)&bb;
        bb = __float2bfloat16(a[6]); ff = __bfloat162float(bb); h1.z = *(unsigned short*)&bb;
        bb = __float2bfloat16(a[6] - ff); l1.z = *(unsigned short*)&bb;
        bb = __float2bfloat16(a[7]); ff = __bfloat162float(bb); h1.w = *(unsigned short*)&bb;
        bb = __float2bfloat16(a[7] - ff); l1.w = *(unsigned short*)&bb;
        size_t base = (size_t)wid * 128 + h * 8;
        *(ushort4*)(outHi + base)     = h0;
        *(ushort4*)(outHi + base + 4) = h1;
        *(ushort4*)(outLo + base)     = l0;
        *(ushort4*)(outLo + base + 4) = l1;
    }
}

// ---------------------------------------------------------------------------
// Fused layer-3 agg (relu, no LN) + collapsed head. Head weights loaded into
// registers AFTER the gather loop (low peak VGPR). No LDS.
// ---------------------------------------------------------------------------
__global__ __launch_bounds__(128) void agg_head(
        const unsigned int* __restrict__ hb,
        const int* __restrict__ rowPtr,
        const int* __restrict__ srcList,
        const float* __restrict__ dinv,
        const float* __restrict__ b,
        const float* __restrict__ Weff,
        const float* __restrict__ beff,
        float* __restrict__ out, int n) {
    int tt = threadIdx.x;
    int wid = (blockIdx.x * 128 + tt) >> 6;
    int lane = tt & 63;
    if (wid >= n) return;
    int h = lane & 15;
    int gg = lane >> 4;
    int e0 = rowPtr[wid], e1 = rowPtr[wid + 1];
    float dc = dinv[wid];
    const uint4* hb4 = (const uint4*)hb;
    uint4 us = hb4[(size_t)wid * 16 + h];

    float a[8];
#pragma unroll
    for (int j = 0; j < 8; j++) a[j] = 0.f;

    int idx0 = (e0 + gg < e1) ? srcList[e0 + gg] : -1;
    int idx1 = (e0 + 4 + gg < e1) ? srcList[e0 + 4 + gg] : -1;
    int e = e0;
    for (; e + 8 <= e1; e += 8) {
        int ni0 = (e + 8 + gg < e1) ? srcList[e + 8 + gg] : -1;
        int ni1 = (e + 12 + gg < e1) ? srcList[e + 12 + gg] : -1;
        uint4 u0 = hb4[(size_t)idx0 * 16 + h];
        uint4 u1 = hb4[(size_t)idx1 * 16 + h];
        ACC8(u0); ACC8(u1);
        idx0 = ni0; idx1 = ni1;
    }
    if (idx0 >= 0) { uint4 u = hb4[(size_t)idx0 * 16 + h]; ACC8(u); }
    if (idx1 >= 0) { uint4 u = hb4[(size_t)idx1 * 16 + h]; ACC8(u); }

#pragma unroll
    for (int j = 0; j < 8; j++) {
        a[j] += __shfl_xor(a[j], 16, 64);
        a[j] += __shfl_xor(a[j], 32, 64);
    }
    ACC8(us);

    float4 bv0 = *(const float4*)(b + h * 8);
    float4 bv1 = *(const float4*)(b + h * 8 + 4);
    a[0] = fmaxf(a[0] * dc + bv0.x, 0.f);
    a[1] = fmaxf(a[1] * dc + bv0.y, 0.f);
    a[2] = fmaxf(a[2] * dc + bv0.z, 0.f);
    a[3] = fmaxf(a[3] * dc + bv0.w, 0.f);
    a[4] = fmaxf(a[4] * dc + bv1.x, 0.f);
    a[5] = fmaxf(a[5] * dc + bv1.y, 0.f);
    a[6] = fmaxf(a[6] * dc + bv1.z, 0.f);
    a[7] = fmaxf(a[7] * dc + bv1.w, 0.f);

    // head weights loaded AFTER gather (gather regs dead): 6x float4
    float p0 = 0.f, p1 = 0.f, p2 = 0.f;
    {
        const float4* wp = (const float4*)(Weff + 24 * h);
#pragma unroll
        for (int q = 0; q < 2; q++) {
            float4 w0 = wp[3 * q + 0];
            float4 w1 = wp[3 * q + 1];
            float4 w2 = wp[3 * q + 2];
            const float* aw = &a[4 * q];
            p0 += aw[0] * w0.x + aw[1] * w0.w + aw[2] * w1.z + aw[3] * w2.y;
            p1 += aw[0] * w0.y + aw[1] * w1.x + aw[2] * w1.w + aw[3] * w2.z;
            p2 += aw[0] * w0.z + aw[1] * w1.y + aw[2] * w2.x + aw[3] * w2.w;
        }
    }
#pragma unroll
    for (int m = 8; m >= 1; m >>= 1) {
        p0 += __shfl_xor(p0, m, 64);
        p1 += __shfl_xor(p1, m, 64);
        p2 += __shfl_xor(p2, m, 64);
    }
    if (lane == 0) {
        out[(size_t)wid * 3 + 0] = p0 + beff[0];
        out[(size_t)wid * 3 + 1] = p1 + beff[1];
        out[(size_t)wid * 3 + 2] = p2 + beff[2];
    }
}

// ---------------------------------------------------------------------------
extern "C" void kernel_launch(void* const* d_in, const int* in_sizes, int n_in,
                              void* d_out, int out_size, void* d_ws, size_t ws_size,
                              hipStream_t stream) {
    const float* x   = (const float*)d_in[0];
    const int* ei    = (const int*)d_in[1];
    const float* W1  = (const float*)d_in[2];
    const float* b1  = (const float*)d_in[3];
    const float* W2  = (const float*)d_in[4];
    const float* b2  = (const float*)d_in[5];
    const float* W3  = (const float*)d_in[6];
    const float* b3  = (const float*)d_in[7];
    const float* g1  = (const float*)d_in[8];
    const float* be1 = (const float*)d_in[9];
    const float* g2  = (const float*)d_in[10];
    const float* be2 = (const float*)d_in[11];
    const float* Wp1f = (const float*)d_in[12];
    const float* bp1 = (const float*)d_in[13];
    const float* Wp2f = (const float*)d_in[14];
    const float* bp2 = (const float*)d_in[15];
    float* out = (float*)d_out;

    const int n = in_sizes[0] / 128;   // 50000
    const int E = in_sizes[1] / 2;     // 1600000
    const int* row = ei;
    const int* col = ei + E;

    char* ws = (char*)d_ws;
    size_t nA  = ((size_t)n * 4 + 255) & ~(size_t)255;
    size_t nA1 = ((size_t)(n + 1) * 4 + 255) & ~(size_t)255;
    size_t eA  = ((size_t)E * 4 + 255) & ~(size_t)255;
    size_t hbSz = ((size_t)n * 128 * 2 + 255) & ~(size_t)255;
    int*   rowPtr  = (int*)ws;
    float* dinvp   = (float*)(ws + nA1);
    int*   srcList = (int*)(ws + nA1 + nA);
    unsigned short* hbA = (unsigned short*)(ws + nA1 + nA + eA);
    unsigned short* hbB = hbA + hbSz / 2;
    unsigned short* Phi = hbB + hbSz / 2;
    unsigned short* Plo = Phi + hbSz / 2;
    unsigned short* Wq  = Plo + hbSz / 2;        // 3 x 32768 ushorts
    float* Weff = (float*)(Wq + 3 * 32768);
    float* beff = Weff + 384;
    // CSR scratch aliases Phi (consumed by bucket_fill before agg writes):
    unsigned int* tmp = (unsigned int*)Phi;      // eA bytes (packed pairs)
    int* chunkBH     = (int*)((char*)Phi + eA);
    int* bucketStart = (int*)((char*)Phi + eA + (size_t)NB * 256 * 4);

    const int nbuck = (n + 255) >> 8;                 // 196
    const int per   = (((E + NB - 1) / NB) + 15) & ~15;
    const int tileBlocks = (n + 127) / 128;           // 391
    const int nodeWaveBlocks = (n + 1) / 2;           // 25000

    // CSR build (bucketed counting sort, zero global atomics)
    bucket_hist<<<NB, 256, 0, stream>>>(col, chunkBH, E, per, nbuck);
    bucket_scan<<<1, 256, 0, stream>>>(chunkBH, bucketStart, rowPtr, E, n, nbuck, NB);
    scatter_pairs<<<NB, 256, 0, stream>>>(row, col, chunkBH, bucketStart, tmp, E, per, nbuck);
    bucket_fill<<<nbuck, 256, 0, stream>>>(tmp, bucketStart, rowPtr, dinvp, srcList, n);
    pack_w_all<<<193, 256, 0, stream>>>(W1, W2, W3, Wq, Wp1f, bp1, Wp2f, bp2, Weff, beff);

    // ---- layer 1 (x f32 -> in-register hi/lo split) ----
    gemm_mfma<0><<<tileBlocks, 512, 0, stream>>>(x, nullptr, nullptr, Wq, dinvp, hbA, n);
    agg_post<<<nodeWaveBlocks, 128, 0, stream>>>((const unsigned int*)hbA,
                                                 rowPtr, srcList, dinvp,
                                                 b1, g1, be1, Phi, Plo, n);
    // ---- layer 2 ----
    gemm_mfma<1><<<tileBlocks, 512, 0, stream>>>(nullptr, Phi, Plo, Wq + 32768, dinvp, hbB, n);
    agg_post<<<nodeWaveBlocks, 128, 0, stream>>>((const unsigned int*)hbB,
                                                 rowPtr, srcList, dinvp,
                                                 b2, g2, be2, Phi, Plo, n);
    // ---- layer 3 ----
    gemm_mfma<1><<<tileBlocks, 512, 0, stream>>>(nullptr, Phi, Plo, Wq + 65536, dinvp, hbA, n);
    agg_head<<<nodeWaveBlocks, 128, 0, stream>>>((const unsigned int*)hbA,
                                                 rowPtr, srcList, dinvp,
                                                 b3, Weff, beff, out, n);
}